// Round 12
// baseline (318.960 us; speedup 1.0000x reference)
//
#include <hip/hip_runtime.h>
#include <stdint.h>

typedef __attribute__((ext_vector_type(4))) float f4;
typedef __attribute__((ext_vector_type(8))) short bf16x8;
typedef __attribute__((ext_vector_type(4))) unsigned short u16x4;
typedef unsigned short u16;

#define B_ 8
#define N_ 1024
#define C_ 768
#define NH 12
#define HD 64

__device__ __forceinline__ float bf2f(u16 v) {
  union { unsigned u; float f; } x; x.u = ((unsigned)v) << 16; return x.f;
}
__device__ __forceinline__ u16 f2bf(float f) {
  union { float f; unsigned u; } x; x.f = f;
  unsigned r = x.u + 0x7FFFu + ((x.u >> 16) & 1u);
  return (u16)(r >> 16);
}
// async global->LDS, 16B per lane
__device__ __forceinline__ void g2l16(const u16* g, const u16* l) {
  __builtin_amdgcn_global_load_lds(
      (const __attribute__((address_space(1))) void*)(uintptr_t)g,
      (__attribute__((address_space(3))) void*)(uint32_t)(uintptr_t)l,
      16, 0, 0);
}

// counted vmem waits (T4): never drain to 0 in the main loop
#define SW12() asm volatile("s_waitcnt vmcnt(12)" ::: "memory")
#define SW6()  asm volatile("s_waitcnt vmcnt(6)" ::: "memory")
#define SW3()  asm volatile("s_waitcnt vmcnt(3)" ::: "memory")
#define SW0()  asm volatile("s_waitcnt vmcnt(0)" ::: "memory")
// raw barrier + compile/IR fence (rule #18)
#define BARF()                              \
  do {                                      \
    __builtin_amdgcn_s_barrier();           \
    asm volatile("" ::: "memory");          \
    __builtin_amdgcn_sched_barrier(0);      \
  } while (0)

// ---------------- cvt: fp32 -> bf16, vectorized x4 ----------------
__global__ __launch_bounds__(256) void cvt_bf16(const float* __restrict__ s,
                                                u16* __restrict__ d, int n4) {
  int i = blockIdx.x * 256 + threadIdx.x;
  int stride = gridDim.x * 256;
  for (; i < n4; i += stride) {
    float4 v = ((const float4*)s)[i];
    u16x4 o;
    o.x = f2bf(v.x); o.y = f2bf(v.y); o.z = f2bf(v.z); o.w = f2bf(v.w);
    ((u16x4*)d)[i] = o;
  }
}

// ---------------- K0+K1 fused: LN stats + transpose + normalize ----------
__global__ __launch_bounds__(512) void ln_fused(const float* __restrict__ y,
                                                const float* __restrict__ lg,
                                                const float* __restrict__ lb,
                                                u16* __restrict__ y2c,
                                                int b0) {
  __shared__ u16 ybuf[768 * 33];          // [c][n 0..31], pitch 33 u16
  __shared__ float ps[16][32], pq[16][32];
  __shared__ float smu[32], srs[32];
  int t = threadIdx.x;
  int nl = t & 31, ch = t >> 5;           // 16 c-groups of 48
  int idx0 = b0 * N_ + blockIdx.x * 32;   // flat n-index
  int b = idx0 >> 10, nb_ = idx0 & 1023;
  const float* p = y + (size_t)b * C_ * N_ + nb_ + nl;
  float s = 0.f, q = 0.f;
  int c0 = ch * 48;
  for (int c = c0; c < c0 + 48; ++c) {
    float v = p[(size_t)c * N_];
    s += v; q += v * v;
    ybuf[c * 33 + nl] = f2bf(v);
  }
  ps[ch][nl] = s; pq[ch][nl] = q;
  __syncthreads();
  if (t < 32) {
    float ts = 0.f, tq = 0.f;
    for (int g = 0; g < 16; ++g) { ts += ps[g][t]; tq += pq[g][t]; }
    float m = ts * (1.f / C_);
    float var = tq * (1.f / C_) - m * m;
    smu[t] = m;
    srs[t] = rsqrtf(fmaxf(var, 0.f) + 1e-5f);
  }
  __syncthreads();
  int rn = t >> 4, cg = t & 15;
  float m = smu[rn], rr = srs[rn];
  int bl = b - b0;
  int n = nb_ + rn;
  u16* dst = y2c + ((size_t)bl * N_ + n) * C_ + cg * 48;
  for (int cc = 0; cc < 48; cc += 8) {
    int c = cg * 48 + cc;
    bf16x8 o;
    for (int j = 0; j < 8; ++j) {
      float v = bf2f(ybuf[(c + j) * 33 + rn]);
      o[j] = (short)f2bf((v - m) * rr * lg[c + j] + lb[c + j]);
    }
    *(bf16x8*)(dst + cc) = o;
  }
}

// ---------------- K2: merged dual-A gated GEMM (R5-exact, best: 90us) ----
// Depth-3 pipeline, counted vmcnt(12), XOR-swizzled LDS, 128x128 tiles.
__global__ __launch_bounds__(256, 2) void gemm_gate(
    const u16* __restrict__ xbc, const u16* __restrict__ y2c,
    const u16* __restrict__ qwb, const u16* __restrict__ kvwb,
    const float* __restrict__ qb_, const float* __restrict__ kvb_,
    u16* __restrict__ o_q, u16* __restrict__ o_k, u16* __restrict__ o_vT) {
  __shared__ u16 smem[36864];  // 3 bufs x 12288 u16 (72 KiB); epilogue reuses front
  int t = threadIdx.x, l = t & 63;
  int quad = l >> 4, l15 = l & 15;
  int w = t >> 6, wm = w & 1, wn = w >> 1;
  int m0l = blockIdx.x * 128;
  int n0l = blockIdx.y * 128;

  const u16* wp; const float* bp; int sel, h0;
  if (n0l < C_) {
    wp = qwb + (size_t)n0l * C_; bp = qb_ + n0l; sel = 0; h0 = n0l >> 6;
  } else {
    int nk = n0l - C_;
    wp = kvwb + (size_t)nk * C_; bp = kvb_ + nk;
    sel = (nk < C_) ? 1 : 2;
    h0 = ((sel == 2) ? nk - C_ : nk) >> 6;
  }

  f4 accx[4][4], accy[4][4];
  for (int i = 0; i < 4; ++i)
    for (int j = 0; j < 4; ++j) {
      accx[i][j] = (f4){0.f, 0.f, 0.f, 0.f};
      accy[i][j] = (f4){0.f, 0.f, 0.f, 0.f};
    }

  int row = t >> 2;
  int colS = (((t & 3) ^ (row & 3)) * 8);   // pre-swizzled source chunk
  const u16* gx = xbc + (size_t)(m0l + row) * C_ + colS;
  const u16* gy = y2c + (size_t)(m0l + row) * C_ + colS;
  const u16* gw = wp + (size_t)row * C_ + colS;
  int rsl = (quad ^ (l15 & 3)) * 8;         // swizzled read slot (u16)

#define STAGE_G(OFF, kk)                                   \
  do {                                                     \
    u16* p_ = smem + (OFF);                                \
    g2l16(gx + (kk),           p_ + t * 8);                \
    g2l16(gx + (kk) + 64 * C_, p_ + 2048 + t * 8);         \
    g2l16(gy + (kk),           p_ + 4096 + t * 8);         \
    g2l16(gy + (kk) + 64 * C_, p_ + 6144 + t * 8);         \
    g2l16(gw + (kk),           p_ + 8192 + t * 8);         \
    g2l16(gw + (kk) + 64 * C_, p_ + 10240 + t * 8);        \
  } while (0)

#define COMPUTE_G(OFF)                                                        \
  do {                                                                        \
    const u16* base = smem + (OFF);                                           \
    bf16x8 afx[4], afy[4], bfr[4];                                            \
    for (int i = 0; i < 4; ++i) {                                             \
      int ra = (wm * 64 + i * 16 + l15) * 32 + rsl;                           \
      afx[i] = *(const bf16x8*)&base[ra];                                     \
      afy[i] = *(const bf16x8*)&base[4096 + ra];                              \
      int rb = (wn * 64 + i * 16 + l15) * 32 + rsl;                           \
      bfr[i] = *(const bf16x8*)&base[8192 + rb];                              \
    }                                                                         \
    for (int i = 0; i < 4; ++i)                                               \
      for (int j = 0; j < 4; ++j) {                                           \
        accx[i][j] = __builtin_amdgcn_mfma_f32_16x16x32_bf16(afx[i], bfr[j], accx[i][j], 0, 0, 0); \
        accy[i][j] = __builtin_amdgcn_mfma_f32_16x16x32_bf16(afy[i], bfr[j], accy[i][j], 0, 0, 0); \
      }                                                                       \
  } while (0)

#define STEP_G(i, OFF)                                        \
  do {                                                        \
    COMPUTE_G(OFF);                                           \
    BARF();                                                   \
    if ((i) < 21)      { STAGE_G(OFF, ((i) + 3) * 32); SW12(); } \
    else if ((i) == 21) SW6();                                \
    else if ((i) == 22) SW0();                                \
    BARF();                                                   \
  } while (0)

  STAGE_G(0, 0);
  STAGE_G(12288, 32);
  STAGE_G(24576, 64);
  SW12();   // tile0 done (tiles 1,2 in flight)
  BARF();
#pragma unroll
  for (int n = 0; n < 24; n += 3) {
    STEP_G(n, 0);
    STEP_G(n + 1, 12288);
    STEP_G(n + 2, 24576);
  }
#undef STEP_G
#undef STAGE_G
#undef COMPUTE_G

  // epilogue: gate -> LDS tile -> cached 16-B stores
  const int PITCH = 136;
  for (int j = 0; j < 4; ++j) {
    int cloc = wn * 64 + j * 16 + l15;
    float bias = bp[cloc];
    for (int i = 0; i < 4; ++i) {
      int rb0 = wm * 64 + i * 16 + quad * 4;
      for (int r = 0; r < 4; ++r) {
        int rloc = rb0 + r;
        float vx = accx[i][j][r] + bias;
        float vy = accy[i][j][r] + bias;
        float gg = 1.f / (1.f + __expf(-vy));
        float val = (sel == 0) ? vx * (1.f + gg) : gg * (vx + 1.f);
        u16 bv = f2bf(val);
        if (sel == 2) smem[cloc * PITCH + rloc] = bv;   // v staged transposed
        else          smem[rloc * PITCH + cloc] = bv;
      }
    }
  }
  __syncthreads();
  {
    int rr = t >> 1, hh = t & 1;
    const u16* src = smem + rr * PITCH + hh * 64;
    u16* dst;
    if (sel == 2) {
      int h = h0 + (rr >> 6), d = rr & 63;
      int bl = m0l >> 10, nbase = m0l & 1023;
      dst = o_vT + (size_t)((bl * NH + h) * HD + d) * N_ + nbase + hh * 64;
    } else {
      int gml = m0l + rr;
      int bl = gml >> 10, n = gml & 1023;
      int h = h0 + hh;
      dst = (sel == 0 ? o_q : o_k) + (size_t)((bl * NH + h) * N_ + n) * HD;
    }
    for (int c = 0; c < 8; ++c) {
      bf16x8 v = *(const bf16x8*)(src + c * 8);
      *(bf16x8*)(dst + c * 8) = v;
    }
  }
}

// ---------------- K3: fused attention, barrier-free ----------------------
// K/V/Q MFMA fragments loaded DIRECTLY from global (L2/L3-resident: 37MB,
// just written by gemm_gate) -- no Qs/Ks/Vs LDS, no staging, and since Ps
// is wave-private by row, ZERO barriers in the kt loop. Each wave owns 32
// q-rows (2 row-groups sharing every K/V fragment load in registers).
// Block = 4 waves x 32 = 128 q-rows; grid (8, B*NH) = 768 blocks.
__global__ __launch_bounds__(256) void attn(const u16* __restrict__ qoc,
                                            const u16* __restrict__ koc,
                                            const u16* __restrict__ vTc,
                                            u16* __restrict__ aoc) {
  __shared__ u16 Ps[128 * 72];
  int t = threadIdx.x, l = t & 63, w = t >> 6;   // 4 waves
  int quad = l >> 4, l15 = l & 15;
  int bhl = blockIdx.y;
  int bl = bhl / NH, h = bhl % NH;
  int q0 = blockIdx.x * 128;
  const u16* qbp = qoc + ((size_t)bhl * N_ + q0) * HD;
  const u16* kb = koc + (size_t)bhl * N_ * HD;
  const u16* vb = vTc + (size_t)bhl * HD * N_;

  // Q fragments: rows w*32 + g*16 + l15, contraction chunks quad*8 (+32)
  bf16x8 aq[2][2];
  for (int g = 0; g < 2; ++g) {
    const u16* qrow = qbp + (size_t)(w * 32 + g * 16 + l15) * HD;
    aq[g][0] = *(const bf16x8*)(qrow + quad * 8);
    aq[g][1] = *(const bf16x8*)(qrow + 32 + quad * 8);
  }

  f4 o[2][4]; f4 ls[2];
  for (int g = 0; g < 2; ++g) {
    ls[g] = (f4){0.f, 0.f, 0.f, 0.f};
    for (int i = 0; i < 4; ++i) o[g][i] = (f4){0.f, 0.f, 0.f, 0.f};
  }
  bf16x8 ones;
  for (int i = 0; i < 8; ++i) ones[i] = (short)0x3F80;  // bf16 1.0

  for (int kt = 0; kt < 16; ++kt) {
    int key0 = kt * 64;
    f4 s_[2][4];
    // QK^T: K B-fragment direct from global (row = key, chunk = d)
    for (int ni = 0; ni < 4; ++ni) {
      const u16* krow = kb + (size_t)(key0 + ni * 16 + l15) * HD;
      bf16x8 b0 = *(const bf16x8*)(krow + quad * 8);
      bf16x8 b1 = *(const bf16x8*)(krow + 32 + quad * 8);
      for (int g = 0; g < 2; ++g) {
        f4 z = (f4){0.f, 0.f, 0.f, 0.f};
        z = __builtin_amdgcn_mfma_f32_16x16x32_bf16(aq[g][0], b0, z, 0, 0, 0);
        z = __builtin_amdgcn_mfma_f32_16x16x32_bf16(aq[g][1], b1, z, 0, 0, 0);
        s_[g][ni] = z;
      }
    }
    // softmax numerator -> Ps (wave-private rows)
    for (int g = 0; g < 2; ++g)
      for (int ni = 0; ni < 4; ++ni)
        for (int r = 0; r < 4; ++r)
          Ps[(w * 32 + g * 16 + quad * 4 + r) * 72 + ni * 16 + l15] =
              f2bf(__expf(s_[g][ni][r] * 0.125f));
    bf16x8 ap[2][2];
    for (int g = 0; g < 2; ++g) {
      ap[g][0] = *(const bf16x8*)&Ps[(w * 32 + g * 16 + l15) * 72 + quad * 8];
      ap[g][1] = *(const bf16x8*)&Ps[(w * 32 + g * 16 + l15) * 72 + 32 + quad * 8];
    }
    // PV: V^T B-fragment direct from global (row = d, chunk = key)
    for (int ni = 0; ni < 4; ++ni) {
      const u16* vrow = vb + (size_t)(ni * 16 + l15) * N_ + key0;
      bf16x8 b0 = *(const bf16x8*)(vrow + quad * 8);
      bf16x8 b1 = *(const bf16x8*)(vrow + 32 + quad * 8);
      for (int g = 0; g < 2; ++g) {
        o[g][ni] = __builtin_amdgcn_mfma_f32_16x16x32_bf16(ap[g][0], b0, o[g][ni], 0, 0, 0);
        o[g][ni] = __builtin_amdgcn_mfma_f32_16x16x32_bf16(ap[g][1], b1, o[g][ni], 0, 0, 0);
      }
    }
    for (int g = 0; g < 2; ++g) {
      ls[g] = __builtin_amdgcn_mfma_f32_16x16x32_bf16(ap[g][0], ones, ls[g], 0, 0, 0);
      ls[g] = __builtin_amdgcn_mfma_f32_16x16x32_bf16(ap[g][1], ones, ls[g], 0, 0, 0);
    }
  }

  for (int g = 0; g < 2; ++g)
    for (int ni = 0; ni < 4; ++ni)
      for (int r = 0; r < 4; ++r)
        Ps[(w * 32 + g * 16 + quad * 4 + r) * 72 + ni * 16 + l15] =
            f2bf(o[g][ni][r] / ls[g][r]);
  __syncthreads();
  {
    int rr = t >> 1, cc = t & 1;               // 128 rows x 2 chunks of 32
    int n = q0 + rr;
    const u16* src = Ps + rr * 72 + cc * 32;
    u16* dst = aoc + ((size_t)bl * N_ + n) * C_ + h * HD + cc * 32;
    for (int c = 0; c < 4; ++c)
      *(bf16x8*)(dst + c * 8) = *(const bf16x8*)(src + c * 8);
  }
}

// ---------------- K4: output projection GEMM, BK=64 depth-2 --------------
__global__ __launch_bounds__(256, 2) void gemm_proj(const u16* __restrict__ aoc,
                                                    const u16* __restrict__ pwb,
                                                    const float* __restrict__ bias,
                                                    float* __restrict__ out,
                                                    int b0) {
  __shared__ u16 smem[24576];  // 2 bufs x 12288 (A 128x64 + B 64x64)
  int t = threadIdx.x, l = t & 63;
  int quad = l >> 4, l15 = l & 15;
  int w = t >> 6, wm = w & 1, wn = w >> 1;
  int m0l = blockIdx.x * 128, n0 = blockIdx.y * 64;
  f4 acc[4][2];
  for (int i = 0; i < 4; ++i)
    for (int j = 0; j < 2; ++j) acc[i][j] = (f4){0.f, 0.f, 0.f, 0.f};
  int row = t >> 2, colb = (t & 3) * 8;
  const u16* ga = aoc + (size_t)(m0l + row) * C_ + colb;
  const u16* gw = pwb + (size_t)(n0 + row) * C_ + colb;

#define STAGE_P(OFF, kk)                                        \
  do {                                                          \
    u16* p_ = smem + (OFF);                                     \
    g2l16(ga + (kk),                p_ + t * 8);                \
    g2l16(ga + (kk) + 64 * C_,      p_ + 2048 + t * 8);         \
    g2l16(ga + (kk) + 32,           p_ + 4096 + t * 8);         \
    g2l16(ga + (kk) + 32 + 64 * C_, p_ + 6144 + t * 8);         \
    g2l16(gw + (kk),                p_ + 8192 + t * 8);         \
    g2l16(gw + (kk) + 32,           p_ + 10240 + t * 8);        \
  } while (0)

#define COMPUTE_P(OFF)                                                        \
  do {                                                                        \
    const u16* base = smem + (OFF);                                           \
    _Pragma("unroll")                                                         \
    for (int kh = 0; kh < 2; ++kh) {                                          \
      bf16x8 af[4], bfr[2];                                                   \
      for (int i = 0; i < 4; ++i)                                             \
        af[i] = *(const bf16x8*)&base[kh * 4096 + (wm * 64 + i * 16 + l15) * 32 + quad * 8]; \
      for (int j = 0; j < 2; ++j)                                             \
        bfr[j] = *(const bf16x8*)&base[8192 + kh * 2048 + (wn * 32 + j * 16 + l15) * 32 + quad * 8]; \
      for (int i = 0; i < 4; ++i)                                             \
        for (int j = 0; j < 2; ++j)                                           \
          acc[i][j] = __builtin_amdgcn_mfma_f32_16x16x32_bf16(af[i], bfr[j], acc[i][j], 0, 0, 0); \
    }                                                                         \
  } while (0)

  STAGE_P(0, 0);
  STAGE_P(12288, 64);
  SW6();
  BARF();
  for (int n = 0; n < 12; n += 2) {
    COMPUTE_P(0);
    BARF();
    if (n + 2 < 12) { STAGE_P(0, (n + 2) * 64); SW6(); } else { SW0(); }
    BARF();
    COMPUTE_P(12288);
    BARF();
    if (n + 3 < 12) { STAGE_P(12288, (n + 3) * 64); SW6(); } else { SW0(); }
    BARF();
  }
#undef STAGE_P
#undef COMPUTE_P

  for (int j = 0; j < 2; ++j) {
    int gcol = n0 + wn * 32 + j * 16 + l15;
    float bv = bias[gcol];
    for (int i = 0; i < 4; ++i) {
      int rbase = m0l + wm * 64 + i * 16 + quad * 4;
      for (int r = 0; r < 4; ++r)
        __builtin_nontemporal_store(acc[i][j][r] + bv,
                                    &out[(size_t)(b0 * N_ + rbase + r) * C_ + gcol]);
    }
  }
}

extern "C" void kernel_launch(void* const* d_in, const int* in_sizes, int n_in,
                              void* d_out, int out_size, void* d_ws, size_t ws_size,
                              hipStream_t stream) {
  const float* x   = (const float*)d_in[0];
  const float* y   = (const float*)d_in[1];
  const float* qw  = (const float*)d_in[2];
  const float* qb  = (const float*)d_in[3];
  const float* kvw = (const float*)d_in[4];
  const float* kvb = (const float*)d_in[5];
  const float* pw  = (const float*)d_in[6];
  const float* pb  = (const float*)d_in[7];
  const float* lg  = (const float*)d_in[8];
  const float* lb  = (const float*)d_in[9];

  char* ws = (char*)d_ws;
  u16* qwb  = (u16*)(ws + 65536);
  u16* kvwb = (u16*)(ws + 1245184);
  u16* pwb  = (u16*)(ws + 3604480);
  const size_t BASE2 = 4784128;
  const size_t PER_B = 1572864;

  int nb = 1;
  for (int c = 8; c >= 1; c >>= 1) {
    if (BASE2 + 5 * (size_t)c * PER_B <= ws_size) { nb = c; break; }
  }
  u16* xbc = (u16*)(ws + BASE2);
  u16* y2c = (u16*)(ws + BASE2 + (size_t)nb * PER_B);
  u16* qoc = (u16*)(ws + BASE2 + 2 * (size_t)nb * PER_B);
  u16* koc = (u16*)(ws + BASE2 + 3 * (size_t)nb * PER_B);
  u16* vTc = (u16*)(ws + BASE2 + 4 * (size_t)nb * PER_B);
  u16* aoc = xbc;

  cvt_bf16<<<dim3(576), dim3(256), 0, stream>>>(qw, qwb, 147456);
  cvt_bf16<<<dim3(1152), dim3(256), 0, stream>>>(kvw, kvwb, 294912);
  cvt_bf16<<<dim3(576), dim3(256), 0, stream>>>(pw, pwb, 147456);

  for (int b0 = 0; b0 < B_; b0 += nb) {
    cvt_bf16<<<dim3(768 * nb), dim3(256), 0, stream>>>(
        x + (size_t)b0 * N_ * C_, xbc, nb * 196608);
    ln_fused<<<dim3(32 * nb), dim3(512), 0, stream>>>(y, lg, lb, y2c, b0);
    gemm_gate<<<dim3(8 * nb, 18), dim3(256), 0, stream>>>(xbc, y2c, qwb, kvwb,
                                                          qb, kvb, qoc, koc, vTc);
    attn<<<dim3(8, 12 * nb), dim3(256), 0, stream>>>(qoc, koc, vTc, aoc);
    gemm_proj<<<dim3(8 * nb, 12), dim3(256), 0, stream>>>(aoc, pwb, pb, (float*)d_out, b0);
  }
}

// Round 13
// 271.441 us; speedup vs baseline: 1.1751x; 1.1751x over previous
//
#include <hip/hip_runtime.h>
#include <stdint.h>

typedef __attribute__((ext_vector_type(4))) float f4;
typedef __attribute__((ext_vector_type(8))) short bf16x8;
typedef __attribute__((ext_vector_type(4))) unsigned short u16x4;
typedef unsigned short u16;

#define B_ 8
#define N_ 1024
#define C_ 768
#define NH 12
#define HD 64

__device__ __forceinline__ float bf2f(u16 v) {
  union { unsigned u; float f; } x; x.u = ((unsigned)v) << 16; return x.f;
}
__device__ __forceinline__ u16 f2bf(float f) {
  union { float f; unsigned u; } x; x.f = f;
  unsigned r = x.u + 0x7FFFu + ((x.u >> 16) & 1u);
  return (u16)(r >> 16);
}
// async global->LDS, 16B per lane
__device__ __forceinline__ void g2l16(const u16* g, const u16* l) {
  __builtin_amdgcn_global_load_lds(
      (const __attribute__((address_space(1))) void*)(uintptr_t)g,
      (__attribute__((address_space(3))) void*)(uint32_t)(uintptr_t)l,
      16, 0, 0);
}

// counted vmem waits (T4): never drain to 0 in the main loop
#define SW12() asm volatile("s_waitcnt vmcnt(12)" ::: "memory")
#define SW6()  asm volatile("s_waitcnt vmcnt(6)" ::: "memory")
#define SW4()  asm volatile("s_waitcnt vmcnt(4)" ::: "memory")
#define SW3()  asm volatile("s_waitcnt vmcnt(3)" ::: "memory")
#define SW2()  asm volatile("s_waitcnt vmcnt(2)" ::: "memory")
#define SW0()  asm volatile("s_waitcnt vmcnt(0)" ::: "memory")
// raw barrier + compile/IR fence (rule #18)
#define BARF()                              \
  do {                                      \
    __builtin_amdgcn_s_barrier();           \
    asm volatile("" ::: "memory");          \
    __builtin_amdgcn_sched_barrier(0);      \
  } while (0)

// ---------------- cvt: fp32 -> bf16, vectorized x4 ----------------
__global__ __launch_bounds__(256) void cvt_bf16(const float* __restrict__ s,
                                                u16* __restrict__ d, int n4) {
  int i = blockIdx.x * 256 + threadIdx.x;
  int stride = gridDim.x * 256;
  for (; i < n4; i += stride) {
    float4 v = ((const float4*)s)[i];
    u16x4 o;
    o.x = f2bf(v.x); o.y = f2bf(v.y); o.z = f2bf(v.z); o.w = f2bf(v.w);
    ((u16x4*)d)[i] = o;
  }
}

// ---------------- K0+K1 fused: LN stats + transpose + normalize ----------
__global__ __launch_bounds__(512) void ln_fused(const float* __restrict__ y,
                                                const float* __restrict__ lg,
                                                const float* __restrict__ lb,
                                                u16* __restrict__ y2c,
                                                int b0) {
  __shared__ u16 ybuf[768 * 33];          // [c][n 0..31], pitch 33 u16
  __shared__ float ps[16][32], pq[16][32];
  __shared__ float smu[32], srs[32];
  int t = threadIdx.x;
  int nl = t & 31, ch = t >> 5;           // 16 c-groups of 48
  int idx0 = b0 * N_ + blockIdx.x * 32;   // flat n-index
  int b = idx0 >> 10, nb_ = idx0 & 1023;
  const float* p = y + (size_t)b * C_ * N_ + nb_ + nl;
  float s = 0.f, q = 0.f;
  int c0 = ch * 48;
  for (int c = c0; c < c0 + 48; ++c) {
    float v = p[(size_t)c * N_];
    s += v; q += v * v;
    ybuf[c * 33 + nl] = f2bf(v);
  }
  ps[ch][nl] = s; pq[ch][nl] = q;
  __syncthreads();
  if (t < 32) {
    float ts = 0.f, tq = 0.f;
    for (int g = 0; g < 16; ++g) { ts += ps[g][t]; tq += pq[g][t]; }
    float m = ts * (1.f / C_);
    float var = tq * (1.f / C_) - m * m;
    smu[t] = m;
    srs[t] = rsqrtf(fmaxf(var, 0.f) + 1e-5f);
  }
  __syncthreads();
  int rn = t >> 4, cg = t & 15;
  float m = smu[rn], rr = srs[rn];
  int bl = b - b0;
  int n = nb_ + rn;
  u16* dst = y2c + ((size_t)bl * N_ + n) * C_ + cg * 48;
  for (int cc = 0; cc < 48; cc += 8) {
    int c = cg * 48 + cc;
    bf16x8 o;
    for (int j = 0; j < 8; ++j) {
      float v = bf2f(ybuf[(c + j) * 33 + rn]);
      o[j] = (short)f2bf((v - m) * rr * lg[c + j] + lb[c + j]);
    }
    *(bf16x8*)(dst + cc) = o;
  }
}

// ---------------- K2: merged dual-A gated GEMM -----------------------
// R5 body (depth-3, counted vmcnt(12), XOR-swizzled LDS, 128x128 tiles) +
// XCD-aware bijective block swizzle (T1): all 18 n-tiles of mg m-tiles land
// on the same XCD so A-panels (~3.1MB) stay L2-resident instead of being
// re-fetched by every XCD. nwg = nm*18 with nm%8==0 -> bijective.
__global__ __launch_bounds__(256, 2) void gemm_gate(
    const u16* __restrict__ xbc, const u16* __restrict__ y2c,
    const u16* __restrict__ qwb, const u16* __restrict__ kvwb,
    const float* __restrict__ qb_, const float* __restrict__ kvb_,
    u16* __restrict__ o_q, u16* __restrict__ o_k, u16* __restrict__ o_vT,
    int nm) {
  __shared__ u16 smem[36864];  // 3 bufs x 12288 u16 (72 KiB); epilogue reuses front
  int t = threadIdx.x, l = t & 63;
  int quad = l >> 4, l15 = l & 15;
  int w = t >> 6, wm = w & 1, wn = w >> 1;
  // XCD swizzle decode: consecutive linear ids round-robin XCDs (wg&7).
  int wg = blockIdx.x;
  int mg = nm >> 3;                  // m-tiles per XCD
  int xcd = wg & 7, s_ = wg >> 3;
  int mx = xcd * mg + (s_ % mg);     // m-tile index
  int ny = s_ / mg;                  // n-tile index (0..17)
  int m0l = mx * 128;
  int n0l = ny * 128;

  const u16* wp; const float* bp; int sel, h0;
  if (n0l < C_) {
    wp = qwb + (size_t)n0l * C_; bp = qb_ + n0l; sel = 0; h0 = n0l >> 6;
  } else {
    int nk = n0l - C_;
    wp = kvwb + (size_t)nk * C_; bp = kvb_ + nk;
    sel = (nk < C_) ? 1 : 2;
    h0 = ((sel == 2) ? nk - C_ : nk) >> 6;
  }

  f4 accx[4][4], accy[4][4];
  for (int i = 0; i < 4; ++i)
    for (int j = 0; j < 4; ++j) {
      accx[i][j] = (f4){0.f, 0.f, 0.f, 0.f};
      accy[i][j] = (f4){0.f, 0.f, 0.f, 0.f};
    }

  int row = t >> 2;
  int colS = (((t & 3) ^ (row & 3)) * 8);   // pre-swizzled source chunk
  const u16* gx = xbc + (size_t)(m0l + row) * C_ + colS;
  const u16* gy = y2c + (size_t)(m0l + row) * C_ + colS;
  const u16* gw = wp + (size_t)row * C_ + colS;
  int rsl = (quad ^ (l15 & 3)) * 8;         // swizzled read slot (u16)

#define STAGE_G(OFF, kk)                                   \
  do {                                                     \
    u16* p_ = smem + (OFF);                                \
    g2l16(gx + (kk),           p_ + t * 8);                \
    g2l16(gx + (kk) + 64 * C_, p_ + 2048 + t * 8);         \
    g2l16(gy + (kk),           p_ + 4096 + t * 8);         \
    g2l16(gy + (kk) + 64 * C_, p_ + 6144 + t * 8);         \
    g2l16(gw + (kk),           p_ + 8192 + t * 8);         \
    g2l16(gw + (kk) + 64 * C_, p_ + 10240 + t * 8);        \
  } while (0)

#define COMPUTE_G(OFF)                                                        \
  do {                                                                        \
    const u16* base = smem + (OFF);                                           \
    bf16x8 afx[4], afy[4], bfr[4];                                            \
    for (int i = 0; i < 4; ++i) {                                             \
      int ra = (wm * 64 + i * 16 + l15) * 32 + rsl;                           \
      afx[i] = *(const bf16x8*)&base[ra];                                     \
      afy[i] = *(const bf16x8*)&base[4096 + ra];                              \
      int rb = (wn * 64 + i * 16 + l15) * 32 + rsl;                           \
      bfr[i] = *(const bf16x8*)&base[8192 + rb];                              \
    }                                                                         \
    for (int i = 0; i < 4; ++i)                                               \
      for (int j = 0; j < 4; ++j) {                                           \
        accx[i][j] = __builtin_amdgcn_mfma_f32_16x16x32_bf16(afx[i], bfr[j], accx[i][j], 0, 0, 0); \
        accy[i][j] = __builtin_amdgcn_mfma_f32_16x16x32_bf16(afy[i], bfr[j], accy[i][j], 0, 0, 0); \
      }                                                                       \
  } while (0)

#define STEP_G(i, OFF)                                        \
  do {                                                        \
    COMPUTE_G(OFF);                                           \
    BARF();                                                   \
    if ((i) < 21)      { STAGE_G(OFF, ((i) + 3) * 32); SW12(); } \
    else if ((i) == 21) SW6();                                \
    else if ((i) == 22) SW0();                                \
    BARF();                                                   \
  } while (0)

  STAGE_G(0, 0);
  STAGE_G(12288, 32);
  STAGE_G(24576, 64);
  SW12();   // tile0 done (tiles 1,2 in flight)
  BARF();
#pragma unroll
  for (int n = 0; n < 24; n += 3) {
    STEP_G(n, 0);
    STEP_G(n + 1, 12288);
    STEP_G(n + 2, 24576);
  }
#undef STEP_G
#undef STAGE_G
#undef COMPUTE_G

  // epilogue: gate -> LDS tile -> cached 16-B stores
  const int PITCH = 136;
  for (int j = 0; j < 4; ++j) {
    int cloc = wn * 64 + j * 16 + l15;
    float bias = bp[cloc];
    for (int i = 0; i < 4; ++i) {
      int rb0 = wm * 64 + i * 16 + quad * 4;
      for (int r = 0; r < 4; ++r) {
        int rloc = rb0 + r;
        float vx = accx[i][j][r] + bias;
        float vy = accy[i][j][r] + bias;
        float gg = 1.f / (1.f + __expf(-vy));
        float val = (sel == 0) ? vx * (1.f + gg) : gg * (vx + 1.f);
        u16 bv = f2bf(val);
        if (sel == 2) smem[cloc * PITCH + rloc] = bv;   // v staged transposed
        else          smem[rloc * PITCH + cloc] = bv;
      }
    }
  }
  __syncthreads();
  {
    int rr = t >> 1, hh = t & 1;
    const u16* src = smem + rr * PITCH + hh * 64;
    u16* dst;
    if (sel == 2) {
      int h = h0 + (rr >> 6), d = rr & 63;
      int bl = m0l >> 10, nbase = m0l & 1023;
      dst = o_vT + (size_t)((bl * NH + h) * HD + d) * N_ + nbase + hh * 64;
    } else {
      int gml = m0l + rr;
      int bl = gml >> 10, n = gml & 1023;
      int h = h0 + hh;
      dst = (sel == 0 ? o_q : o_k) + (size_t)((bl * NH + h) * N_ + n) * HD;
    }
    for (int c = 0; c < 8; ++c) {
      bf16x8 v = *(const bf16x8*)(src + c * 8);
      *(bf16x8*)(dst + c * 8) = v;
    }
  }
}

// ---------------- K3: fused attention, Q-tile 128, 512 threads (R11) -----
// 8 waves, each owns ONE 16-q-row group. K/V staged once per 128 q-rows;
// one global_load_lds per K/V half-tile (512 lanes x 16B = 8KB).
__global__ __launch_bounds__(512) void attn(const u16* __restrict__ qoc,
                                            const u16* __restrict__ koc,
                                            const u16* __restrict__ vTc,
                                            u16* __restrict__ aoc) {
  __shared__ u16 Qs[8192], Ks[8192], Vs[8192];   // Q 128x64; K/V 2 half-tiles
  __shared__ u16 Ps[128 * 72];
  int t = threadIdx.x, l = t & 63, w = t >> 6;   // w: 0..7
  int quad = l >> 4, l15 = l & 15;
  int bhl = blockIdx.y;
  int bl = bhl / NH, h = bhl % NH;
  int q0 = blockIdx.x * 128;
  int sr = t >> 3;                       // staging row 0..63
  int swo = ((t & 7) ^ (sr & 7)) * 8;    // swizzled source chunk offset (u16)
  const u16* qbp = qoc + ((size_t)bhl * N_ + q0) * HD;
  const u16* kb = koc + (size_t)bhl * N_ * HD;
  const u16* vb = vTc + (size_t)bhl * HD * N_;

#define STAGE_KV(OFF, key0)                                                \
  do {                                                                     \
    g2l16(kb + (size_t)((key0) + sr) * HD + swo, Ks + (OFF) + t * 8);      \
    g2l16(vb + (size_t)sr * N_ + (key0) + swo,   Vs + (OFF) + t * 8);      \
  } while (0)

  g2l16(qbp + (size_t)sr * HD + swo,        Qs + t * 8);
  g2l16(qbp + (size_t)(64 + sr) * HD + swo, Qs + 4096 + t * 8);
  STAGE_KV(0, 0);
  STAGE_KV(4096, 64);
  SW2();   // Q(2) + KV0(2) done; KV1's 2 in flight
  BARF();

  int sA = (quad ^ (l15 & 7)) * 8;  // swizzled slot, contraction chunks 0-3
  int sB = sA ^ 32;                 // chunks 4-7
  bf16x8 aq0 = *(const bf16x8*)&Qs[(w * 16 + l15) * 64 + sA];
  bf16x8 aq1 = *(const bf16x8*)&Qs[(w * 16 + l15) * 64 + sB];
  f4 o[4];
  for (int i = 0; i < 4; ++i) o[i] = (f4){0.f, 0.f, 0.f, 0.f};
  f4 ls = (f4){0.f, 0.f, 0.f, 0.f};
  bf16x8 ones;
  for (int i = 0; i < 8; ++i) ones[i] = (short)0x3F80;  // bf16 1.0

#define TILE_STEP(KOFF)                                                       \
  do {                                                                        \
    f4 s_[4];                                                                 \
    __builtin_amdgcn_s_setprio(1);                                            \
    for (int ni = 0; ni < 4; ++ni) {                                          \
      bf16x8 b0v = *(const bf16x8*)&Ks[(KOFF) + (ni * 16 + l15) * 64 + sA];   \
      bf16x8 b1v = *(const bf16x8*)&Ks[(KOFF) + (ni * 16 + l15) * 64 + sB];   \
      f4 z = (f4){0.f, 0.f, 0.f, 0.f};                                        \
      z = __builtin_amdgcn_mfma_f32_16x16x32_bf16(aq0, b0v, z, 0, 0, 0);      \
      z = __builtin_amdgcn_mfma_f32_16x16x32_bf16(aq1, b1v, z, 0, 0, 0);      \
      s_[ni] = z;                                                             \
    }                                                                         \
    __builtin_amdgcn_s_setprio(0);                                            \
    for (int ni = 0; ni < 4; ++ni)                                            \
      for (int r = 0; r < 4; ++r)                                             \
        Ps[(w * 16 + quad * 4 + r) * 72 + ni * 16 + l15] =                    \
            f2bf(__expf(s_[ni][r] * 0.125f));                                 \
    bf16x8 ap0 = *(const bf16x8*)&Ps[(w * 16 + l15) * 72 + quad * 8];         \
    bf16x8 ap1 = *(const bf16x8*)&Ps[(w * 16 + l15) * 72 + 32 + quad * 8];    \
    __builtin_amdgcn_s_setprio(1);                                            \
    for (int ni = 0; ni < 4; ++ni) {                                          \
      bf16x8 b0v = *(const bf16x8*)&Vs[(KOFF) + (ni * 16 + l15) * 64 + sA];   \
      bf16x8 b1v = *(const bf16x8*)&Vs[(KOFF) + (ni * 16 + l15) * 64 + sB];   \
      o[ni] = __builtin_amdgcn_mfma_f32_16x16x32_bf16(ap0, b0v, o[ni], 0, 0, 0); \
      o[ni] = __builtin_amdgcn_mfma_f32_16x16x32_bf16(ap1, b1v, o[ni], 0, 0, 0); \
    }                                                                         \
    ls = __builtin_amdgcn_mfma_f32_16x16x32_bf16(ap0, ones, ls, 0, 0, 0);     \
    ls = __builtin_amdgcn_mfma_f32_16x16x32_bf16(ap1, ones, ls, 0, 0, 0);     \
    __builtin_amdgcn_s_setprio(0);                                            \
  } while (0)

  for (int kt = 0; kt < 16; kt += 2) {
    TILE_STEP(0);
    BARF();                                   // done reading KV half 0
    if (kt + 2 < 16) { STAGE_KV(0, (kt + 2) * 64); SW2(); } else { SW0(); }
    BARF();                                   // KV half 1 visible
    TILE_STEP(4096);
    BARF();                                   // done reading KV half 1
    if (kt + 3 < 16) { STAGE_KV(4096, (kt + 3) * 64); SW2(); } else { SW0(); }
    BARF();                                   // KV half 0 visible
  }
#undef TILE_STEP
#undef STAGE_KV

  for (int ni = 0; ni < 4; ++ni)
    for (int r = 0; r < 4; ++r)
      Ps[(w * 16 + quad * 4 + r) * 72 + ni * 16 + l15] =
          f2bf(o[ni][r] / ls[r]);
  __syncthreads();
  {
    int rr = t >> 2, cc = t & 3;               // 128 rows x 4 chunks of 16
    int n = q0 + rr;
    const u16* src = Ps + rr * 72 + cc * 16;
    u16* dst = aoc + ((size_t)bl * N_ + n) * C_ + h * HD + cc * 16;
    *(bf16x8*)dst = *(const bf16x8*)src;
    *(bf16x8*)(dst + 8) = *(const bf16x8*)(src + 8);
  }
}

// ---------------- K4: output projection GEMM, BK=64 depth-2 (R11) --------
__global__ __launch_bounds__(256, 2) void gemm_proj(const u16* __restrict__ aoc,
                                                    const u16* __restrict__ pwb,
                                                    const float* __restrict__ bias,
                                                    float* __restrict__ out,
                                                    int b0) {
  __shared__ u16 smem[24576];  // 2 bufs x 12288 (A 128x64 + B 64x64)
  int t = threadIdx.x, l = t & 63;
  int quad = l >> 4, l15 = l & 15;
  int w = t >> 6, wm = w & 1, wn = w >> 1;
  int m0l = blockIdx.x * 128, n0 = blockIdx.y * 64;
  f4 acc[4][2];
  for (int i = 0; i < 4; ++i)
    for (int j = 0; j < 2; ++j) acc[i][j] = (f4){0.f, 0.f, 0.f, 0.f};
  int row = t >> 2, colb = (t & 3) * 8;
  const u16* ga = aoc + (size_t)(m0l + row) * C_ + colb;
  const u16* gw = pwb + (size_t)(n0 + row) * C_ + colb;

#define STAGE_P(OFF, kk)                                        \
  do {                                                          \
    u16* p_ = smem + (OFF);                                     \
    g2l16(ga + (kk),                p_ + t * 8);                \
    g2l16(ga + (kk) + 64 * C_,      p_ + 2048 + t * 8);         \
    g2l16(ga + (kk) + 32,           p_ + 4096 + t * 8);         \
    g2l16(ga + (kk) + 32 + 64 * C_, p_ + 6144 + t * 8);         \
    g2l16(gw + (kk),                p_ + 8192 + t * 8);         \
    g2l16(gw + (kk) + 32,           p_ + 10240 + t * 8);        \
  } while (0)

#define COMPUTE_P(OFF)                                                        \
  do {                                                                        \
    const u16* base = smem + (OFF);                                           \
    _Pragma("unroll")                                                         \
    for (int kh = 0; kh < 2; ++kh) {                                          \
      bf16x8 af[4], bfr[2];                                                   \
      for (int i = 0; i < 4; ++i)                                             \
        af[i] = *(const bf16x8*)&base[kh * 4096 + (wm * 64 + i * 16 + l15) * 32 + quad * 8]; \
      for (int j = 0; j < 2; ++j)                                             \
        bfr[j] = *(const bf16x8*)&base[8192 + kh * 2048 + (wn * 32 + j * 16 + l15) * 32 + quad * 8]; \
      for (int i = 0; i < 4; ++i)                                             \
        for (int j = 0; j < 2; ++j)                                           \
          acc[i][j] = __builtin_amdgcn_mfma_f32_16x16x32_bf16(af[i], bfr[j], acc[i][j], 0, 0, 0); \
    }                                                                         \
  } while (0)

  STAGE_P(0, 0);
  STAGE_P(12288, 64);
  SW6();
  BARF();
  for (int n = 0; n < 12; n += 2) {
    COMPUTE_P(0);
    BARF();
    if (n + 2 < 12) { STAGE_P(0, (n + 2) * 64); SW6(); } else { SW0(); }
    BARF();
    COMPUTE_P(12288);
    BARF();
    if (n + 3 < 12) { STAGE_P(12288, (n + 3) * 64); SW6(); } else { SW0(); }
    BARF();
  }
#undef STAGE_P
#undef COMPUTE_P

  for (int j = 0; j < 2; ++j) {
    int gcol = n0 + wn * 32 + j * 16 + l15;
    float bv = bias[gcol];
    for (int i = 0; i < 4; ++i) {
      int rbase = m0l + wm * 64 + i * 16 + quad * 4;
      for (int r = 0; r < 4; ++r)
        __builtin_nontemporal_store(acc[i][j][r] + bv,
                                    &out[(size_t)(b0 * N_ + rbase + r) * C_ + gcol]);
    }
  }
}

extern "C" void kernel_launch(void* const* d_in, const int* in_sizes, int n_in,
                              void* d_out, int out_size, void* d_ws, size_t ws_size,
                              hipStream_t stream) {
  const float* x   = (const float*)d_in[0];
  const float* y   = (const float*)d_in[1];
  const float* qw  = (const float*)d_in[2];
  const float* qb  = (const float*)d_in[3];
  const float* kvw = (const float*)d_in[4];
  const float* kvb = (const float*)d_in[5];
  const float* pw  = (const float*)d_in[6];
  const float* pb  = (const float*)d_in[7];
  const float* lg  = (const float*)d_in[8];
  const float* lb  = (const float*)d_in[9];

  char* ws = (char*)d_ws;
  u16* qwb  = (u16*)(ws + 65536);
  u16* kvwb = (u16*)(ws + 1245184);
  u16* pwb  = (u16*)(ws + 3604480);
  const size_t BASE2 = 4784128;
  const size_t PER_B = 1572864;

  int nb = 1;
  for (int c = 8; c >= 1; c >>= 1) {
    if (BASE2 + 5 * (size_t)c * PER_B <= ws_size) { nb = c; break; }
  }
  u16* xbc = (u16*)(ws + BASE2);
  u16* y2c = (u16*)(ws + BASE2 + (size_t)nb * PER_B);
  u16* qoc = (u16*)(ws + BASE2 + 2 * (size_t)nb * PER_B);
  u16* koc = (u16*)(ws + BASE2 + 3 * (size_t)nb * PER_B);
  u16* vTc = (u16*)(ws + BASE2 + 4 * (size_t)nb * PER_B);
  u16* aoc = xbc;

  cvt_bf16<<<dim3(576), dim3(256), 0, stream>>>(qw, qwb, 147456);
  cvt_bf16<<<dim3(1152), dim3(256), 0, stream>>>(kvw, kvwb, 294912);
  cvt_bf16<<<dim3(576), dim3(256), 0, stream>>>(pw, pwb, 147456);

  for (int b0 = 0; b0 < B_; b0 += nb) {
    cvt_bf16<<<dim3(768 * nb), dim3(256), 0, stream>>>(
        x + (size_t)b0 * N_ * C_, xbc, nb * 196608);
    ln_fused<<<dim3(32 * nb), dim3(512), 0, stream>>>(y, lg, lb, y2c, b0);
    int nm = 8 * nb;                       // m-tiles (divisible by 8 for nb=1,2,4,8... nb>=1: 8*nb%8==0)
    gemm_gate<<<dim3(nm * 18), dim3(256), 0, stream>>>(xbc, y2c, qwb, kvwb,
                                                       qb, kvb, qoc, koc, vTc, nm);
    attn<<<dim3(8, 12 * nb), dim3(512), 0, stream>>>(qoc, koc, vTc, aoc);
    gemm_proj<<<dim3(8 * nb, 12), dim3(256), 0, stream>>>(aoc, pwb, pb, (float*)d_out, b0);
  }
}

// Round 14
// 268.567 us; speedup vs baseline: 1.1876x; 1.0107x over previous
//
#include <hip/hip_runtime.h>
#include <stdint.h>

typedef __attribute__((ext_vector_type(4))) float f4;
typedef __attribute__((ext_vector_type(8))) short bf16x8;
typedef __attribute__((ext_vector_type(4))) unsigned short u16x4;
typedef unsigned short u16;

#define B_ 8
#define N_ 1024
#define C_ 768
#define NH 12
#define HD 64

__device__ __forceinline__ float bf2f(u16 v) {
  union { unsigned u; float f; } x; x.u = ((unsigned)v) << 16; return x.f;
}
__device__ __forceinline__ u16 f2bf(float f) {
  union { float f; unsigned u; } x; x.f = f;
  unsigned r = x.u + 0x7FFFu + ((x.u >> 16) & 1u);
  return (u16)(r >> 16);
}
// async global->LDS, 16B per lane
__device__ __forceinline__ void g2l16(const u16* g, const u16* l) {
  __builtin_amdgcn_global_load_lds(
      (const __attribute__((address_space(1))) void*)(uintptr_t)g,
      (__attribute__((address_space(3))) void*)(uint32_t)(uintptr_t)l,
      16, 0, 0);
}

// counted vmem waits (T4): never drain to 0 in the main loop
#define SW12() asm volatile("s_waitcnt vmcnt(12)" ::: "memory")
#define SW6()  asm volatile("s_waitcnt vmcnt(6)" ::: "memory")
#define SW4()  asm volatile("s_waitcnt vmcnt(4)" ::: "memory")
#define SW3()  asm volatile("s_waitcnt vmcnt(3)" ::: "memory")
#define SW2()  asm volatile("s_waitcnt vmcnt(2)" ::: "memory")
#define SW0()  asm volatile("s_waitcnt vmcnt(0)" ::: "memory")
// raw barrier + compile/IR fence (rule #18)
#define BARF()                              \
  do {                                      \
    __builtin_amdgcn_s_barrier();           \
    asm volatile("" ::: "memory");          \
    __builtin_amdgcn_sched_barrier(0);      \
  } while (0)

// ---------------- cvt: fp32 -> bf16, vectorized x4 (weights) -------------
__global__ __launch_bounds__(256) void cvt_bf16(const float* __restrict__ s,
                                                u16* __restrict__ d, int n4) {
  int i = blockIdx.x * 256 + threadIdx.x;
  int stride = gridDim.x * 256;
  for (; i < n4; i += stride) {
    float4 v = ((const float4*)s)[i];
    u16x4 o;
    o.x = f2bf(v.x); o.y = f2bf(v.y); o.z = f2bf(v.z); o.w = f2bf(v.w);
    ((u16x4*)d)[i] = o;
  }
}

// ---------------- prep: fused {LN(y) -> y2c} + {cvt x -> xbc} ------------
// Blocks [0, 32*nb): ln_fused path (one pass over y slice, stats in fp32,
// bf16 cache in LDS, normalized write to y2c). Blocks [32*nb, 128*nb):
// grid-stride fp32->bf16 conversion of x. Two independent HBM streams in
// one dispatch: one launch gap instead of two, tails overlap.
__global__ __launch_bounds__(512) void prep(const float* __restrict__ y,
                                            const float* __restrict__ lg,
                                            const float* __restrict__ lb,
                                            u16* __restrict__ y2c,
                                            const float* __restrict__ x,
                                            u16* __restrict__ xbc,
                                            int b0, int nb, int n4) {
  int t = threadIdx.x;
  int nln = 32 * nb;
  if ((int)blockIdx.x >= nln) {
    // ---- cvt path ----
    int cb = blockIdx.x - nln;
    int ncvt = gridDim.x - nln;
    int i = cb * 512 + t;
    int stride = ncvt * 512;
    for (; i < n4; i += stride) {
      float4 v = ((const float4*)x)[i];
      u16x4 o;
      o.x = f2bf(v.x); o.y = f2bf(v.y); o.z = f2bf(v.z); o.w = f2bf(v.w);
      ((u16x4*)xbc)[i] = o;
    }
    return;
  }
  // ---- ln path ----
  __shared__ u16 ybuf[768 * 33];          // [c][n 0..31], pitch 33 u16
  __shared__ float ps[16][32], pq[16][32];
  __shared__ float smu[32], srs[32];
  int nl = t & 31, ch = t >> 5;           // 16 c-groups of 48
  int idx0 = b0 * N_ + blockIdx.x * 32;   // flat n-index
  int b = idx0 >> 10, nb_ = idx0 & 1023;
  const float* p = y + (size_t)b * C_ * N_ + nb_ + nl;
  float s = 0.f, q = 0.f;
  int c0 = ch * 48;
  for (int c = c0; c < c0 + 48; ++c) {
    float v = p[(size_t)c * N_];
    s += v; q += v * v;
    ybuf[c * 33 + nl] = f2bf(v);
  }
  ps[ch][nl] = s; pq[ch][nl] = q;
  __syncthreads();
  if (t < 32) {
    float ts = 0.f, tq = 0.f;
    for (int g = 0; g < 16; ++g) { ts += ps[g][t]; tq += pq[g][t]; }
    float m = ts * (1.f / C_);
    float var = tq * (1.f / C_) - m * m;
    smu[t] = m;
    srs[t] = rsqrtf(fmaxf(var, 0.f) + 1e-5f);
  }
  __syncthreads();
  int rn = t >> 4, cg = t & 15;
  float m = smu[rn], rr = srs[rn];
  int bl = b - b0;
  int n = nb_ + rn;
  u16* dst = y2c + ((size_t)bl * N_ + n) * C_ + cg * 48;
  for (int cc = 0; cc < 48; cc += 8) {
    int c = cg * 48 + cc;
    bf16x8 o;
    for (int j = 0; j < 8; ++j) {
      float v = bf2f(ybuf[(c + j) * 33 + rn]);
      o[j] = (short)f2bf((v - m) * rr * lg[c + j] + lb[c + j]);
    }
    *(bf16x8*)(dst + cc) = o;
  }
}

// ---------------- K2: merged dual-A gated GEMM (R5/R11-exact: 90us) ------
// Depth-3 pipeline, counted vmcnt(12), XOR-swizzled LDS, 128x128 tiles.
__global__ __launch_bounds__(256, 2) void gemm_gate(
    const u16* __restrict__ xbc, const u16* __restrict__ y2c,
    const u16* __restrict__ qwb, const u16* __restrict__ kvwb,
    const float* __restrict__ qb_, const float* __restrict__ kvb_,
    u16* __restrict__ o_q, u16* __restrict__ o_k, u16* __restrict__ o_vT) {
  __shared__ u16 smem[36864];  // 3 bufs x 12288 u16 (72 KiB); epilogue reuses front
  int t = threadIdx.x, l = t & 63;
  int quad = l >> 4, l15 = l & 15;
  int w = t >> 6, wm = w & 1, wn = w >> 1;
  int m0l = blockIdx.x * 128;
  int n0l = blockIdx.y * 128;

  const u16* wp; const float* bp; int sel, h0;
  if (n0l < C_) {
    wp = qwb + (size_t)n0l * C_; bp = qb_ + n0l; sel = 0; h0 = n0l >> 6;
  } else {
    int nk = n0l - C_;
    wp = kvwb + (size_t)nk * C_; bp = kvb_ + nk;
    sel = (nk < C_) ? 1 : 2;
    h0 = ((sel == 2) ? nk - C_ : nk) >> 6;
  }

  f4 accx[4][4], accy[4][4];
  for (int i = 0; i < 4; ++i)
    for (int j = 0; j < 4; ++j) {
      accx[i][j] = (f4){0.f, 0.f, 0.f, 0.f};
      accy[i][j] = (f4){0.f, 0.f, 0.f, 0.f};
    }

  int row = t >> 2;
  int colS = (((t & 3) ^ (row & 3)) * 8);   // pre-swizzled source chunk
  const u16* gx = xbc + (size_t)(m0l + row) * C_ + colS;
  const u16* gy = y2c + (size_t)(m0l + row) * C_ + colS;
  const u16* gw = wp + (size_t)row * C_ + colS;
  int rsl = (quad ^ (l15 & 3)) * 8;         // swizzled read slot (u16)

#define STAGE_G(OFF, kk)                                   \
  do {                                                     \
    u16* p_ = smem + (OFF);                                \
    g2l16(gx + (kk),           p_ + t * 8);                \
    g2l16(gx + (kk) + 64 * C_, p_ + 2048 + t * 8);         \
    g2l16(gy + (kk),           p_ + 4096 + t * 8);         \
    g2l16(gy + (kk) + 64 * C_, p_ + 6144 + t * 8);         \
    g2l16(gw + (kk),           p_ + 8192 + t * 8);         \
    g2l16(gw + (kk) + 64 * C_, p_ + 10240 + t * 8);        \
  } while (0)

#define COMPUTE_G(OFF)                                                        \
  do {                                                                        \
    const u16* base = smem + (OFF);                                           \
    bf16x8 afx[4], afy[4], bfr[4];                                            \
    for (int i = 0; i < 4; ++i) {                                             \
      int ra = (wm * 64 + i * 16 + l15) * 32 + rsl;                           \
      afx[i] = *(const bf16x8*)&base[ra];                                     \
      afy[i] = *(const bf16x8*)&base[4096 + ra];                              \
      int rb = (wn * 64 + i * 16 + l15) * 32 + rsl;                           \
      bfr[i] = *(const bf16x8*)&base[8192 + rb];                              \
    }                                                                         \
    for (int i = 0; i < 4; ++i)                                               \
      for (int j = 0; j < 4; ++j) {                                           \
        accx[i][j] = __builtin_amdgcn_mfma_f32_16x16x32_bf16(afx[i], bfr[j], accx[i][j], 0, 0, 0); \
        accy[i][j] = __builtin_amdgcn_mfma_f32_16x16x32_bf16(afy[i], bfr[j], accy[i][j], 0, 0, 0); \
      }                                                                       \
  } while (0)

#define STEP_G(i, OFF)                                        \
  do {                                                        \
    COMPUTE_G(OFF);                                           \
    BARF();                                                   \
    if ((i) < 21)      { STAGE_G(OFF, ((i) + 3) * 32); SW12(); } \
    else if ((i) == 21) SW6();                                \
    else if ((i) == 22) SW0();                                \
    BARF();                                                   \
  } while (0)

  STAGE_G(0, 0);
  STAGE_G(12288, 32);
  STAGE_G(24576, 64);
  SW12();   // tile0 done (tiles 1,2 in flight)
  BARF();
#pragma unroll
  for (int n = 0; n < 24; n += 3) {
    STEP_G(n, 0);
    STEP_G(n + 1, 12288);
    STEP_G(n + 2, 24576);
  }
#undef STEP_G
#undef STAGE_G
#undef COMPUTE_G

  // epilogue: gate -> LDS tile -> cached 16-B stores
  const int PITCH = 136;
  for (int j = 0; j < 4; ++j) {
    int cloc = wn * 64 + j * 16 + l15;
    float bias = bp[cloc];
    for (int i = 0; i < 4; ++i) {
      int rb0 = wm * 64 + i * 16 + quad * 4;
      for (int r = 0; r < 4; ++r) {
        int rloc = rb0 + r;
        float vx = accx[i][j][r] + bias;
        float vy = accy[i][j][r] + bias;
        float gg = 1.f / (1.f + __expf(-vy));
        float val = (sel == 0) ? vx * (1.f + gg) : gg * (vx + 1.f);
        u16 bv = f2bf(val);
        if (sel == 2) smem[cloc * PITCH + rloc] = bv;   // v staged transposed
        else          smem[rloc * PITCH + cloc] = bv;
      }
    }
  }
  __syncthreads();
  {
    int rr = t >> 1, hh = t & 1;
    const u16* src = smem + rr * PITCH + hh * 64;
    u16* dst;
    if (sel == 2) {
      int h = h0 + (rr >> 6), d = rr & 63;
      int bl = m0l >> 10, nbase = m0l & 1023;
      dst = o_vT + (size_t)((bl * NH + h) * HD + d) * N_ + nbase + hh * 64;
    } else {
      int gml = m0l + rr;
      int bl = gml >> 10, n = gml & 1023;
      int h = h0 + hh;
      dst = (sel == 0 ? o_q : o_k) + (size_t)((bl * NH + h) * N_ + n) * HD;
    }
    for (int c = 0; c < 8; ++c) {
      bf16x8 v = *(const bf16x8*)(src + c * 8);
      *(bf16x8*)(dst + c * 8) = v;
    }
  }
}

// ---------------- K3: fused attention, Q-tile 128, 512 threads (R11) -----
__global__ __launch_bounds__(512) void attn(const u16* __restrict__ qoc,
                                            const u16* __restrict__ koc,
                                            const u16* __restrict__ vTc,
                                            u16* __restrict__ aoc) {
  __shared__ u16 Qs[8192], Ks[8192], Vs[8192];   // Q 128x64; K/V 2 half-tiles
  __shared__ u16 Ps[128 * 72];
  int t = threadIdx.x, l = t & 63, w = t >> 6;   // w: 0..7
  int quad = l >> 4, l15 = l & 15;
  int bhl = blockIdx.y;
  int bl = bhl / NH, h = bhl % NH;
  int q0 = blockIdx.x * 128;
  int sr = t >> 3;                       // staging row 0..63
  int swo = ((t & 7) ^ (sr & 7)) * 8;    // swizzled source chunk offset (u16)
  const u16* qbp = qoc + ((size_t)bhl * N_ + q0) * HD;
  const u16* kb = koc + (size_t)bhl * N_ * HD;
  const u16* vb = vTc + (size_t)bhl * HD * N_;

#define STAGE_KV(OFF, key0)                                                \
  do {                                                                     \
    g2l16(kb + (size_t)((key0) + sr) * HD + swo, Ks + (OFF) + t * 8);      \
    g2l16(vb + (size_t)sr * N_ + (key0) + swo,   Vs + (OFF) + t * 8);      \
  } while (0)

  g2l16(qbp + (size_t)sr * HD + swo,        Qs + t * 8);
  g2l16(qbp + (size_t)(64 + sr) * HD + swo, Qs + 4096 + t * 8);
  STAGE_KV(0, 0);
  STAGE_KV(4096, 64);
  SW2();   // Q(2) + KV0(2) done; KV1's 2 in flight
  BARF();

  int sA = (quad ^ (l15 & 7)) * 8;  // swizzled slot, contraction chunks 0-3
  int sB = sA ^ 32;                 // chunks 4-7
  bf16x8 aq0 = *(const bf16x8*)&Qs[(w * 16 + l15) * 64 + sA];
  bf16x8 aq1 = *(const bf16x8*)&Qs[(w * 16 + l15) * 64 + sB];
  f4 o[4];
  for (int i = 0; i < 4; ++i) o[i] = (f4){0.f, 0.f, 0.f, 0.f};
  f4 ls = (f4){0.f, 0.f, 0.f, 0.f};
  bf16x8 ones;
  for (int i = 0; i < 8; ++i) ones[i] = (short)0x3F80;  // bf16 1.0

#define TILE_STEP(KOFF)                                                       \
  do {                                                                        \
    f4 s_[4];                                                                 \
    __builtin_amdgcn_s_setprio(1);                                            \
    for (int ni = 0; ni < 4; ++ni) {                                          \
      bf16x8 b0v = *(const bf16x8*)&Ks[(KOFF) + (ni * 16 + l15) * 64 + sA];   \
      bf16x8 b1v = *(const bf16x8*)&Ks[(KOFF) + (ni * 16 + l15) * 64 + sB];   \
      f4 z = (f4){0.f, 0.f, 0.f, 0.f};                                        \
      z = __builtin_amdgcn_mfma_f32_16x16x32_bf16(aq0, b0v, z, 0, 0, 0);      \
      z = __builtin_amdgcn_mfma_f32_16x16x32_bf16(aq1, b1v, z, 0, 0, 0);      \
      s_[ni] = z;                                                             \
    }                                                                         \
    __builtin_amdgcn_s_setprio(0);                                            \
    for (int ni = 0; ni < 4; ++ni)                                            \
      for (int r = 0; r < 4; ++r)                                             \
        Ps[(w * 16 + quad * 4 + r) * 72 + ni * 16 + l15] =                    \
            f2bf(__expf(s_[ni][r] * 0.125f));                                 \
    bf16x8 ap0 = *(const bf16x8*)&Ps[(w * 16 + l15) * 72 + quad * 8];         \
    bf16x8 ap1 = *(const bf16x8*)&Ps[(w * 16 + l15) * 72 + 32 + quad * 8];    \
    __builtin_amdgcn_s_setprio(1);                                            \
    for (int ni = 0; ni < 4; ++ni) {                                          \
      bf16x8 b0v = *(const bf16x8*)&Vs[(KOFF) + (ni * 16 + l15) * 64 + sA];   \
      bf16x8 b1v = *(const bf16x8*)&Vs[(KOFF) + (ni * 16 + l15) * 64 + sB];   \
      o[ni] = __builtin_amdgcn_mfma_f32_16x16x32_bf16(ap0, b0v, o[ni], 0, 0, 0); \
      o[ni] = __builtin_amdgcn_mfma_f32_16x16x32_bf16(ap1, b1v, o[ni], 0, 0, 0); \
    }                                                                         \
    ls = __builtin_amdgcn_mfma_f32_16x16x32_bf16(ap0, ones, ls, 0, 0, 0);     \
    ls = __builtin_amdgcn_mfma_f32_16x16x32_bf16(ap1, ones, ls, 0, 0, 0);     \
    __builtin_amdgcn_s_setprio(0);                                            \
  } while (0)

  for (int kt = 0; kt < 16; kt += 2) {
    TILE_STEP(0);
    BARF();                                   // done reading KV half 0
    if (kt + 2 < 16) { STAGE_KV(0, (kt + 2) * 64); SW2(); } else { SW0(); }
    BARF();                                   // KV half 1 visible
    TILE_STEP(4096);
    BARF();                                   // done reading KV half 1
    if (kt + 3 < 16) { STAGE_KV(4096, (kt + 3) * 64); SW2(); } else { SW0(); }
    BARF();                                   // KV half 0 visible
  }
#undef TILE_STEP
#undef STAGE_KV

  for (int ni = 0; ni < 4; ++ni)
    for (int r = 0; r < 4; ++r)
      Ps[(w * 16 + quad * 4 + r) * 72 + ni * 16 + l15] =
          f2bf(o[ni][r] / ls[r]);
  __syncthreads();
  {
    int rr = t >> 2, cc = t & 3;               // 128 rows x 4 chunks of 16
    int n = q0 + rr;
    const u16* src = Ps + rr * 72 + cc * 16;
    u16* dst = aoc + ((size_t)bl * N_ + n) * C_ + h * HD + cc * 16;
    *(bf16x8*)dst = *(const bf16x8*)src;
    *(bf16x8*)(dst + 8) = *(const bf16x8*)(src + 8);
  }
}

// ---------------- K4: output projection GEMM, BK=64 depth-2 (R11) --------
__global__ __launch_bounds__(256, 2) void gemm_proj(const u16* __restrict__ aoc,
                                                    const u16* __restrict__ pwb,
                                                    const float* __restrict__ bias,
                                                    float* __restrict__ out,
                                                    int b0) {
  __shared__ u16 smem[24576];  // 2 bufs x 12288 (A 128x64 + B 64x64)
  int t = threadIdx.x, l = t & 63;
  int quad = l >> 4, l15 = l & 15;
  int w = t >> 6, wm = w & 1, wn = w >> 1;
  int m0l = blockIdx.x * 128, n0 = blockIdx.y * 64;
  f4 acc[4][2];
  for (int i = 0; i < 4; ++i)
    for (int j = 0; j < 2; ++j) acc[i][j] = (f4){0.f, 0.f, 0.f, 0.f};
  int row = t >> 2, colb = (t & 3) * 8;
  const u16* ga = aoc + (size_t)(m0l + row) * C_ + colb;
  const u16* gw = pwb + (size_t)(n0 + row) * C_ + colb;

#define STAGE_P(OFF, kk)                                        \
  do {                                                          \
    u16* p_ = smem + (OFF);                                     \
    g2l16(ga + (kk),                p_ + t * 8);                \
    g2l16(ga + (kk) + 64 * C_,      p_ + 2048 + t * 8);         \
    g2l16(ga + (kk) + 32,           p_ + 4096 + t * 8);         \
    g2l16(ga + (kk) + 32 + 64 * C_, p_ + 6144 + t * 8);         \
    g2l16(gw + (kk),                p_ + 8192 + t * 8);         \
    g2l16(gw + (kk) + 32,           p_ + 10240 + t * 8);        \
  } while (0)

#define COMPUTE_P(OFF)                                                        \
  do {                                                                        \
    const u16* base = smem + (OFF);                                           \
    _Pragma("unroll")                                                         \
    for (int kh = 0; kh < 2; ++kh) {                                          \
      bf16x8 af[4], bfr[2];                                                   \
      for (int i = 0; i < 4; ++i)                                             \
        af[i] = *(const bf16x8*)&base[kh * 4096 + (wm * 64 + i * 16 + l15) * 32 + quad * 8]; \
      for (int j = 0; j < 2; ++j)                                             \
        bfr[j] = *(const bf16x8*)&base[8192 + kh * 2048 + (wn * 32 + j * 16 + l15) * 32 + quad * 8]; \
      for (int i = 0; i < 4; ++i)                                             \
        for (int j = 0; j < 2; ++j)                                           \
          acc[i][j] = __builtin_amdgcn_mfma_f32_16x16x32_bf16(af[i], bfr[j], acc[i][j], 0, 0, 0); \
    }                                                                         \
  } while (0)

  STAGE_P(0, 0);
  STAGE_P(12288, 64);
  SW6();
  BARF();
  for (int n = 0; n < 12; n += 2) {
    COMPUTE_P(0);
    BARF();
    if (n + 2 < 12) { STAGE_P(0, (n + 2) * 64); SW6(); } else { SW0(); }
    BARF();
    COMPUTE_P(12288);
    BARF();
    if (n + 3 < 12) { STAGE_P(12288, (n + 3) * 64); SW6(); } else { SW0(); }
    BARF();
  }
#undef STAGE_P
#undef COMPUTE_P

  for (int j = 0; j < 2; ++j) {
    int gcol = n0 + wn * 32 + j * 16 + l15;
    float bv = bias[gcol];
    for (int i = 0; i < 4; ++i) {
      int rbase = m0l + wm * 64 + i * 16 + quad * 4;
      for (int r = 0; r < 4; ++r)
        __builtin_nontemporal_store(acc[i][j][r] + bv,
                                    &out[(size_t)(b0 * N_ + rbase + r) * C_ + gcol]);
    }
  }
}

extern "C" void kernel_launch(void* const* d_in, const int* in_sizes, int n_in,
                              void* d_out, int out_size, void* d_ws, size_t ws_size,
                              hipStream_t stream) {
  const float* x   = (const float*)d_in[0];
  const float* y   = (const float*)d_in[1];
  const float* qw  = (const float*)d_in[2];
  const float* qb  = (const float*)d_in[3];
  const float* kvw = (const float*)d_in[4];
  const float* kvb = (const float*)d_in[5];
  const float* pw  = (const float*)d_in[6];
  const float* pb  = (const float*)d_in[7];
  const float* lg  = (const float*)d_in[8];
  const float* lb  = (const float*)d_in[9];

  char* ws = (char*)d_ws;
  u16* qwb  = (u16*)(ws + 65536);
  u16* kvwb = (u16*)(ws + 1245184);
  u16* pwb  = (u16*)(ws + 3604480);
  const size_t BASE2 = 4784128;
  const size_t PER_B = 1572864;

  int nb = 1;
  for (int c = 8; c >= 1; c >>= 1) {
    if (BASE2 + 5 * (size_t)c * PER_B <= ws_size) { nb = c; break; }
  }
  u16* xbc = (u16*)(ws + BASE2);
  u16* y2c = (u16*)(ws + BASE2 + (size_t)nb * PER_B);
  u16* qoc = (u16*)(ws + BASE2 + 2 * (size_t)nb * PER_B);
  u16* koc = (u16*)(ws + BASE2 + 3 * (size_t)nb * PER_B);
  u16* vTc = (u16*)(ws + BASE2 + 4 * (size_t)nb * PER_B);
  u16* aoc = xbc;

  cvt_bf16<<<dim3(576), dim3(256), 0, stream>>>(qw, qwb, 147456);
  cvt_bf16<<<dim3(1152), dim3(256), 0, stream>>>(kvw, kvwb, 294912);
  cvt_bf16<<<dim3(576), dim3(256), 0, stream>>>(pw, pwb, 147456);

  for (int b0 = 0; b0 < B_; b0 += nb) {
    prep<<<dim3(128 * nb), dim3(512), 0, stream>>>(
        y, lg, lb, y2c, x + (size_t)b0 * N_ * C_, xbc, b0, nb, nb * 196608);
    gemm_gate<<<dim3(8 * nb, 18), dim3(256), 0, stream>>>(xbc, y2c, qwb, kvwb,
                                                          qb, kvb, qoc, koc, vTc);
    attn<<<dim3(8, 12 * nb), dim3(512), 0, stream>>>(qoc, koc, vTc, aoc);
    gemm_proj<<<dim3(8 * nb, 12), dim3(256), 0, stream>>>(aoc, pwb, pb, (float*)d_out, b0);
  }
}

// Round 15
// 261.637 us; speedup vs baseline: 1.2191x; 1.0265x over previous
//
#include <hip/hip_runtime.h>
#include <stdint.h>

typedef __attribute__((ext_vector_type(4))) float f4;
typedef __attribute__((ext_vector_type(8))) short bf16x8;
typedef __attribute__((ext_vector_type(4))) unsigned short u16x4;
typedef unsigned short u16;

#define B_ 8
#define N_ 1024
#define C_ 768
#define NH 12
#define HD 64

__device__ __forceinline__ float bf2f(u16 v) {
  union { unsigned u; float f; } x; x.u = ((unsigned)v) << 16; return x.f;
}
__device__ __forceinline__ u16 f2bf(float f) {
  union { float f; unsigned u; } x; x.f = f;
  unsigned r = x.u + 0x7FFFu + ((x.u >> 16) & 1u);
  return (u16)(r >> 16);
}
// async global->LDS, 16B per lane
__device__ __forceinline__ void g2l16(const u16* g, const u16* l) {
  __builtin_amdgcn_global_load_lds(
      (const __attribute__((address_space(1))) void*)(uintptr_t)g,
      (__attribute__((address_space(3))) void*)(uint32_t)(uintptr_t)l,
      16, 0, 0);
}

// counted vmem waits (T4): never drain to 0 in the main loop
#define SW12() asm volatile("s_waitcnt vmcnt(12)" ::: "memory")
#define SW6()  asm volatile("s_waitcnt vmcnt(6)" ::: "memory")
#define SW4()  asm volatile("s_waitcnt vmcnt(4)" ::: "memory")
#define SW3()  asm volatile("s_waitcnt vmcnt(3)" ::: "memory")
#define SW2()  asm volatile("s_waitcnt vmcnt(2)" ::: "memory")
#define SW0()  asm volatile("s_waitcnt vmcnt(0)" ::: "memory")
// raw barrier + compile/IR fence (rule #18)
#define BARF()                              \
  do {                                      \
    __builtin_amdgcn_s_barrier();           \
    asm volatile("" ::: "memory");          \
    __builtin_amdgcn_sched_barrier(0);      \
  } while (0)

// ---------------- cvt3: all three weight matrices in one dispatch --------
// blocks [0,288): qw (147456 f4), [288,864): kvw (294912), [864,1152): pw.
__global__ __launch_bounds__(256) void cvt3(const float* __restrict__ qw,
                                            u16* __restrict__ qwb,
                                            const float* __restrict__ kvw,
                                            u16* __restrict__ kvwb,
                                            const float* __restrict__ pw,
                                            u16* __restrict__ pwb) {
  int bi = blockIdx.x;
  const float* s; u16* d; int n4, b0, nbk;
  if (bi < 288)      { s = qw;  d = qwb;  n4 = 147456; b0 = 0;   nbk = 288; }
  else if (bi < 864) { s = kvw; d = kvwb; n4 = 294912; b0 = 288; nbk = 576; }
  else               { s = pw;  d = pwb;  n4 = 147456; b0 = 864; nbk = 288; }
  int i = (bi - b0) * 256 + threadIdx.x;
  int stride = nbk * 256;
  for (; i < n4; i += stride) {
    float4 v = ((const float4*)s)[i];
    u16x4 o;
    o.x = f2bf(v.x); o.y = f2bf(v.y); o.z = f2bf(v.z); o.w = f2bf(v.w);
    ((u16x4*)d)[i] = o;
  }
}

// ---------------- prep: fused {LN(y) -> y2c} + {cvt x -> xbc} ------------
__global__ __launch_bounds__(512) void prep(const float* __restrict__ y,
                                            const float* __restrict__ lg,
                                            const float* __restrict__ lb,
                                            u16* __restrict__ y2c,
                                            const float* __restrict__ x,
                                            u16* __restrict__ xbc,
                                            int b0, int nb, int n4) {
  int t = threadIdx.x;
  int nln = 32 * nb;
  if ((int)blockIdx.x >= nln) {
    // ---- cvt path ----
    int cb = blockIdx.x - nln;
    int ncvt = gridDim.x - nln;
    int i = cb * 512 + t;
    int stride = ncvt * 512;
    for (; i < n4; i += stride) {
      float4 v = ((const float4*)x)[i];
      u16x4 o;
      o.x = f2bf(v.x); o.y = f2bf(v.y); o.z = f2bf(v.z); o.w = f2bf(v.w);
      ((u16x4*)xbc)[i] = o;
    }
    return;
  }
  // ---- ln path ----
  __shared__ u16 ybuf[768 * 33];          // [c][n 0..31], pitch 33 u16
  __shared__ float ps[16][32], pq[16][32];
  __shared__ float smu[32], srs[32];
  int nl = t & 31, ch = t >> 5;           // 16 c-groups of 48
  int idx0 = b0 * N_ + blockIdx.x * 32;   // flat n-index
  int b = idx0 >> 10, nb_ = idx0 & 1023;
  const float* p = y + (size_t)b * C_ * N_ + nb_ + nl;
  float s = 0.f, q = 0.f;
  int c0 = ch * 48;
  for (int c = c0; c < c0 + 48; ++c) {
    float v = p[(size_t)c * N_];
    s += v; q += v * v;
    ybuf[c * 33 + nl] = f2bf(v);
  }
  ps[ch][nl] = s; pq[ch][nl] = q;
  __syncthreads();
  if (t < 32) {
    float ts = 0.f, tq = 0.f;
    for (int g = 0; g < 16; ++g) { ts += ps[g][t]; tq += pq[g][t]; }
    float m = ts * (1.f / C_);
    float var = tq * (1.f / C_) - m * m;
    smu[t] = m;
    srs[t] = rsqrtf(fmaxf(var, 0.f) + 1e-5f);
  }
  __syncthreads();
  int rn = t >> 4, cg = t & 15;
  float m = smu[rn], rr = srs[rn];
  int bl = b - b0;
  int n = nb_ + rn;
  u16* dst = y2c + ((size_t)bl * N_ + n) * C_ + cg * 48;
  for (int cc = 0; cc < 48; cc += 8) {
    int c = cg * 48 + cc;
    bf16x8 o;
    for (int j = 0; j < 8; ++j) {
      float v = bf2f(ybuf[(c + j) * 33 + rn]);
      o[j] = (short)f2bf((v - m) * rr * lg[c + j] + lb[c + j]);
    }
    *(bf16x8*)(dst + cc) = o;
  }
}

// ---------------- K2: merged dual-A gated GEMM (R5/R11-exact: 90us) ------
// Depth-3 pipeline, counted vmcnt(12), XOR-swizzled LDS, 128x128 tiles.
__global__ __launch_bounds__(256, 2) void gemm_gate(
    const u16* __restrict__ xbc, const u16* __restrict__ y2c,
    const u16* __restrict__ qwb, const u16* __restrict__ kvwb,
    const float* __restrict__ qb_, const float* __restrict__ kvb_,
    u16* __restrict__ o_q, u16* __restrict__ o_k, u16* __restrict__ o_vT) {
  __shared__ u16 smem[36864];  // 3 bufs x 12288 u16 (72 KiB); epilogue reuses front
  int t = threadIdx.x, l = t & 63;
  int quad = l >> 4, l15 = l & 15;
  int w = t >> 6, wm = w & 1, wn = w >> 1;
  int m0l = blockIdx.x * 128;
  int n0l = blockIdx.y * 128;

  const u16* wp; const float* bp; int sel, h0;
  if (n0l < C_) {
    wp = qwb + (size_t)n0l * C_; bp = qb_ + n0l; sel = 0; h0 = n0l >> 6;
  } else {
    int nk = n0l - C_;
    wp = kvwb + (size_t)nk * C_; bp = kvb_ + nk;
    sel = (nk < C_) ? 1 : 2;
    h0 = ((sel == 2) ? nk - C_ : nk) >> 6;
  }

  f4 accx[4][4], accy[4][4];
  for (int i = 0; i < 4; ++i)
    for (int j = 0; j < 4; ++j) {
      accx[i][j] = (f4){0.f, 0.f, 0.f, 0.f};
      accy[i][j] = (f4){0.f, 0.f, 0.f, 0.f};
    }

  int row = t >> 2;
  int colS = (((t & 3) ^ (row & 3)) * 8);   // pre-swizzled source chunk
  const u16* gx = xbc + (size_t)(m0l + row) * C_ + colS;
  const u16* gy = y2c + (size_t)(m0l + row) * C_ + colS;
  const u16* gw = wp + (size_t)row * C_ + colS;
  int rsl = (quad ^ (l15 & 3)) * 8;         // swizzled read slot (u16)

#define STAGE_G(OFF, kk)                                   \
  do {                                                     \
    u16* p_ = smem + (OFF);                                \
    g2l16(gx + (kk),           p_ + t * 8);                \
    g2l16(gx + (kk) + 64 * C_, p_ + 2048 + t * 8);         \
    g2l16(gy + (kk),           p_ + 4096 + t * 8);         \
    g2l16(gy + (kk) + 64 * C_, p_ + 6144 + t * 8);         \
    g2l16(gw + (kk),           p_ + 8192 + t * 8);         \
    g2l16(gw + (kk) + 64 * C_, p_ + 10240 + t * 8);        \
  } while (0)

#define COMPUTE_G(OFF)                                                        \
  do {                                                                        \
    const u16* base = smem + (OFF);                                           \
    bf16x8 afx[4], afy[4], bfr[4];                                            \
    for (int i = 0; i < 4; ++i) {                                             \
      int ra = (wm * 64 + i * 16 + l15) * 32 + rsl;                           \
      afx[i] = *(const bf16x8*)&base[ra];                                     \
      afy[i] = *(const bf16x8*)&base[4096 + ra];                              \
      int rb = (wn * 64 + i * 16 + l15) * 32 + rsl;                           \
      bfr[i] = *(const bf16x8*)&base[8192 + rb];                              \
    }                                                                         \
    for (int i = 0; i < 4; ++i)                                               \
      for (int j = 0; j < 4; ++j) {                                           \
        accx[i][j] = __builtin_amdgcn_mfma_f32_16x16x32_bf16(afx[i], bfr[j], accx[i][j], 0, 0, 0); \
        accy[i][j] = __builtin_amdgcn_mfma_f32_16x16x32_bf16(afy[i], bfr[j], accy[i][j], 0, 0, 0); \
      }                                                                       \
  } while (0)

#define STEP_G(i, OFF)                                        \
  do {                                                        \
    COMPUTE_G(OFF);                                           \
    BARF();                                                   \
    if ((i) < 21)      { STAGE_G(OFF, ((i) + 3) * 32); SW12(); } \
    else if ((i) == 21) SW6();                                \
    else if ((i) == 22) SW0();                                \
    BARF();                                                   \
  } while (0)

  STAGE_G(0, 0);
  STAGE_G(12288, 32);
  STAGE_G(24576, 64);
  SW12();   // tile0 done (tiles 1,2 in flight)
  BARF();
#pragma unroll
  for (int n = 0; n < 24; n += 3) {
    STEP_G(n, 0);
    STEP_G(n + 1, 12288);
    STEP_G(n + 2, 24576);
  }
#undef STEP_G
#undef STAGE_G
#undef COMPUTE_G

  // epilogue: gate -> LDS tile -> cached 16-B stores
  const int PITCH = 136;
  for (int j = 0; j < 4; ++j) {
    int cloc = wn * 64 + j * 16 + l15;
    float bias = bp[cloc];
    for (int i = 0; i < 4; ++i) {
      int rb0 = wm * 64 + i * 16 + quad * 4;
      for (int r = 0; r < 4; ++r) {
        int rloc = rb0 + r;
        float vx = accx[i][j][r] + bias;
        float vy = accy[i][j][r] + bias;
        float gg = 1.f / (1.f + __expf(-vy));
        float val = (sel == 0) ? vx * (1.f + gg) : gg * (vx + 1.f);
        u16 bv = f2bf(val);
        if (sel == 2) smem[cloc * PITCH + rloc] = bv;   // v staged transposed
        else          smem[rloc * PITCH + cloc] = bv;
      }
    }
  }
  __syncthreads();
  {
    int rr = t >> 1, hh = t & 1;
    const u16* src = smem + rr * PITCH + hh * 64;
    u16* dst;
    if (sel == 2) {
      int h = h0 + (rr >> 6), d = rr & 63;
      int bl = m0l >> 10, nbase = m0l & 1023;
      dst = o_vT + (size_t)((bl * NH + h) * HD + d) * N_ + nbase + hh * 64;
    } else {
      int gml = m0l + rr;
      int bl = gml >> 10, n = gml & 1023;
      int h = h0 + hh;
      dst = (sel == 0 ? o_q : o_k) + (size_t)((bl * NH + h) * N_ + n) * HD;
    }
    for (int c = 0; c < 8; ++c) {
      bf16x8 v = *(const bf16x8*)(src + c * 8);
      *(bf16x8*)(dst + c * 8) = v;
    }
  }
}

// ---------------- K3: fused attention, Q-tile 128, 512 threads -----------
// XCD-locality grid: (heads, qblocks). Linear block id = head + NBH*qb with
// NBH%8==0 -> xcd = head%8: all 8 q-blocks of one head land on the SAME
// XCD, so its 256KB K/V stays L2-resident across q-blocks (R12 showed the
// old (qb, head) order re-fetched K/V from HBM: FETCH 104MB vs 38MB cold).
__global__ __launch_bounds__(512) void attn(const u16* __restrict__ qoc,
                                            const u16* __restrict__ koc,
                                            const u16* __restrict__ vTc,
                                            u16* __restrict__ aoc) {
  __shared__ u16 Qs[8192], Ks[8192], Vs[8192];   // Q 128x64; K/V 2 half-tiles
  __shared__ u16 Ps[128 * 72];
  int t = threadIdx.x, l = t & 63, w = t >> 6;   // w: 0..7
  int quad = l >> 4, l15 = l & 15;
  int bhl = blockIdx.x;                  // head index (B*NH)
  int bl = bhl / NH, h = bhl % NH;
  int q0 = blockIdx.y * 128;             // q-block
  int sr = t >> 3;                       // staging row 0..63
  int swo = ((t & 7) ^ (sr & 7)) * 8;    // swizzled source chunk offset (u16)
  const u16* qbp = qoc + ((size_t)bhl * N_ + q0) * HD;
  const u16* kb = koc + (size_t)bhl * N_ * HD;
  const u16* vb = vTc + (size_t)bhl * HD * N_;

#define STAGE_KV(OFF, key0)                                                \
  do {                                                                     \
    g2l16(kb + (size_t)((key0) + sr) * HD + swo, Ks + (OFF) + t * 8);      \
    g2l16(vb + (size_t)sr * N_ + (key0) + swo,   Vs + (OFF) + t * 8);      \
  } while (0)

  g2l16(qbp + (size_t)sr * HD + swo,        Qs + t * 8);
  g2l16(qbp + (size_t)(64 + sr) * HD + swo, Qs + 4096 + t * 8);
  STAGE_KV(0, 0);
  STAGE_KV(4096, 64);
  SW2();   // Q(2) + KV0(2) done; KV1's 2 in flight
  BARF();

  int sA = (quad ^ (l15 & 7)) * 8;  // swizzled slot, contraction chunks 0-3
  int sB = sA ^ 32;                 // chunks 4-7
  bf16x8 aq0 = *(const bf16x8*)&Qs[(w * 16 + l15) * 64 + sA];
  bf16x8 aq1 = *(const bf16x8*)&Qs[(w * 16 + l15) * 64 + sB];
  f4 o[4];
  for (int i = 0; i < 4; ++i) o[i] = (f4){0.f, 0.f, 0.f, 0.f};
  f4 ls = (f4){0.f, 0.f, 0.f, 0.f};
  bf16x8 ones;
  for (int i = 0; i < 8; ++i) ones[i] = (short)0x3F80;  // bf16 1.0

#define TILE_STEP(KOFF)                                                       \
  do {                                                                        \
    f4 s_[4];                                                                 \
    __builtin_amdgcn_s_setprio(1);                                            \
    for (int ni = 0; ni < 4; ++ni) {                                          \
      bf16x8 b0v = *(const bf16x8*)&Ks[(KOFF) + (ni * 16 + l15) * 64 + sA];   \
      bf16x8 b1v = *(const bf16x8*)&Ks[(KOFF) + (ni * 16 + l15) * 64 + sB];   \
      f4 z = (f4){0.f, 0.f, 0.f, 0.f};                                        \
      z = __builtin_amdgcn_mfma_f32_16x16x32_bf16(aq0, b0v, z, 0, 0, 0);      \
      z = __builtin_amdgcn_mfma_f32_16x16x32_bf16(aq1, b1v, z, 0, 0, 0);      \
      s_[ni] = z;                                                             \
    }                                                                         \
    __builtin_amdgcn_s_setprio(0);                                            \
    for (int ni = 0; ni < 4; ++ni)                                            \
      for (int r = 0; r < 4; ++r)                                             \
        Ps[(w * 16 + quad * 4 + r) * 72 + ni * 16 + l15] =                    \
            f2bf(__expf(s_[ni][r] * 0.125f));                                 \
    bf16x8 ap0 = *(const bf16x8*)&Ps[(w * 16 + l15) * 72 + quad * 8];         \
    bf16x8 ap1 = *(const bf16x8*)&Ps[(w * 16 + l15) * 72 + 32 + quad * 8];    \
    __builtin_amdgcn_s_setprio(1);                                            \
    for (int ni = 0; ni < 4; ++ni) {                                          \
      bf16x8 b0v = *(const bf16x8*)&Vs[(KOFF) + (ni * 16 + l15) * 64 + sA];   \
      bf16x8 b1v = *(const bf16x8*)&Vs[(KOFF) + (ni * 16 + l15) * 64 + sB];   \
      o[ni] = __builtin_amdgcn_mfma_f32_16x16x32_bf16(ap0, b0v, o[ni], 0, 0, 0); \
      o[ni] = __builtin_amdgcn_mfma_f32_16x16x32_bf16(ap1, b1v, o[ni], 0, 0, 0); \
    }                                                                         \
    ls = __builtin_amdgcn_mfma_f32_16x16x32_bf16(ap0, ones, ls, 0, 0, 0);     \
    ls = __builtin_amdgcn_mfma_f32_16x16x32_bf16(ap1, ones, ls, 0, 0, 0);     \
    __builtin_amdgcn_s_setprio(0);                                            \
  } while (0)

  for (int kt = 0; kt < 16; kt += 2) {
    TILE_STEP(0);
    BARF();                                   // done reading KV half 0
    if (kt + 2 < 16) { STAGE_KV(0, (kt + 2) * 64); SW2(); } else { SW0(); }
    BARF();                                   // KV half 1 visible
    TILE_STEP(4096);
    BARF();                                   // done reading KV half 1
    if (kt + 3 < 16) { STAGE_KV(4096, (kt + 3) * 64); SW2(); } else { SW0(); }
    BARF();                                   // KV half 0 visible
  }
#undef TILE_STEP
#undef STAGE_KV

  for (int ni = 0; ni < 4; ++ni)
    for (int r = 0; r < 4; ++r)
      Ps[(w * 16 + quad * 4 + r) * 72 + ni * 16 + l15] =
          f2bf(o[ni][r] / ls[r]);
  __syncthreads();
  {
    int rr = t >> 2, cc = t & 3;               // 128 rows x 4 chunks of 16
    int n = q0 + rr;
    const u16* src = Ps + rr * 72 + cc * 16;
    u16* dst = aoc + ((size_t)bl * N_ + n) * C_ + h * HD + cc * 16;
    *(bf16x8*)dst = *(const bf16x8*)src;
    *(bf16x8*)(dst + 8) = *(const bf16x8*)(src + 8);
  }
}

// ---------------- K4: output projection GEMM, BK=64 depth-2 (R11) --------
__global__ __launch_bounds__(256, 2) void gemm_proj(const u16* __restrict__ aoc,
                                                    const u16* __restrict__ pwb,
                                                    const float* __restrict__ bias,
                                                    float* __restrict__ out,
                                                    int b0) {
  __shared__ u16 smem[24576];  // 2 bufs x 12288 (A 128x64 + B 64x64)
  int t = threadIdx.x, l = t & 63;
  int quad = l >> 4, l15 = l & 15;
  int w = t >> 6, wm = w & 1, wn = w >> 1;
  int m0l = blockIdx.x * 128, n0 = blockIdx.y * 64;
  f4 acc[4][2];
  for (int i = 0; i < 4; ++i)
    for (int j = 0; j < 2; ++j) acc[i][j] = (f4){0.f, 0.f, 0.f, 0.f};
  int row = t >> 2, colb = (t & 3) * 8;
  const u16* ga = aoc + (size_t)(m0l + row) * C_ + colb;
  const u16* gw = pwb + (size_t)(n0 + row) * C_ + colb;

#define STAGE_P(OFF, kk)                                        \
  do {                                                          \
    u16* p_ = smem + (OFF);                                     \
    g2l16(ga + (kk),                p_ + t * 8);                \
    g2l16(ga + (kk) + 64 * C_,      p_ + 2048 + t * 8);         \
    g2l16(ga + (kk) + 32,           p_ + 4096 + t * 8);         \
    g2l16(ga + (kk) + 32 + 64 * C_, p_ + 6144 + t * 8);         \
    g2l16(gw + (kk),                p_ + 8192 + t * 8);         \
    g2l16(gw + (kk) + 32,           p_ + 10240 + t * 8);        \
  } while (0)

#define COMPUTE_P(OFF)                                                        \
  do {                                                                        \
    const u16* base = smem + (OFF);                                           \
    _Pragma("unroll")                                                         \
    for (int kh = 0; kh < 2; ++kh) {                                          \
      bf16x8 af[4], bfr[2];                                                   \
      for (int i = 0; i < 4; ++i)                                             \
        af[i] = *(const bf16x8*)&base[kh * 4096 + (wm * 64 + i * 16 + l15) * 32 + quad * 8]; \
      for (int j = 0; j < 2; ++j)                                             \
        bfr[j] = *(const bf16x8*)&base[8192 + kh * 2048 + (wn * 32 + j * 16 + l15) * 32 + quad * 8]; \
      for (int i = 0; i < 4; ++i)                                             \
        for (int j = 0; j < 2; ++j)                                           \
          acc[i][j] = __builtin_amdgcn_mfma_f32_16x16x32_bf16(af[i], bfr[j], acc[i][j], 0, 0, 0); \
    }                                                                         \
  } while (0)

  STAGE_P(0, 0);
  STAGE_P(12288, 64);
  SW6();
  BARF();
  for (int n = 0; n < 12; n += 2) {
    COMPUTE_P(0);
    BARF();
    if (n + 2 < 12) { STAGE_P(0, (n + 2) * 64); SW6(); } else { SW0(); }
    BARF();
    COMPUTE_P(12288);
    BARF();
    if (n + 3 < 12) { STAGE_P(12288, (n + 3) * 64); SW6(); } else { SW0(); }
    BARF();
  }
#undef STAGE_P
#undef COMPUTE_P

  for (int j = 0; j < 2; ++j) {
    int gcol = n0 + wn * 32 + j * 16 + l15;
    float bv = bias[gcol];
    for (int i = 0; i < 4; ++i) {
      int rbase = m0l + wm * 64 + i * 16 + quad * 4;
      for (int r = 0; r < 4; ++r)
        __builtin_nontemporal_store(acc[i][j][r] + bv,
                                    &out[(size_t)(b0 * N_ + rbase + r) * C_ + gcol]);
    }
  }
}

extern "C" void kernel_launch(void* const* d_in, const int* in_sizes, int n_in,
                              void* d_out, int out_size, void* d_ws, size_t ws_size,
                              hipStream_t stream) {
  const float* x   = (const float*)d_in[0];
  const float* y   = (const float*)d_in[1];
  const float* qw  = (const float*)d_in[2];
  const float* qb  = (const float*)d_in[3];
  const float* kvw = (const float*)d_in[4];
  const float* kvb = (const float*)d_in[5];
  const float* pw  = (const float*)d_in[6];
  const float* pb  = (const float*)d_in[7];
  const float* lg  = (const float*)d_in[8];
  const float* lb  = (const float*)d_in[9];

  char* ws = (char*)d_ws;
  u16* qwb  = (u16*)(ws + 65536);
  u16* kvwb = (u16*)(ws + 1245184);
  u16* pwb  = (u16*)(ws + 3604480);
  const size_t BASE2 = 4784128;
  const size_t PER_B = 1572864;

  int nb = 1;
  for (int c = 8; c >= 1; c >>= 1) {
    if (BASE2 + 5 * (size_t)c * PER_B <= ws_size) { nb = c; break; }
  }
  u16* xbc = (u16*)(ws + BASE2);
  u16* y2c = (u16*)(ws + BASE2 + (size_t)nb * PER_B);
  u16* qoc = (u16*)(ws + BASE2 + 2 * (size_t)nb * PER_B);
  u16* koc = (u16*)(ws + BASE2 + 3 * (size_t)nb * PER_B);
  u16* vTc = (u16*)(ws + BASE2 + 4 * (size_t)nb * PER_B);
  u16* aoc = xbc;

  cvt3<<<dim3(1152), dim3(256), 0, stream>>>(qw, qwb, kvw, kvwb, pw, pwb);

  for (int b0 = 0; b0 < B_; b0 += nb) {
    prep<<<dim3(128 * nb), dim3(512), 0, stream>>>(
        y, lg, lb, y2c, x + (size_t)b0 * N_ * C_, xbc, b0, nb, nb * 196608);
    gemm_gate<<<dim3(8 * nb, 18), dim3(256), 0, stream>>>(xbc, y2c, qwb, kvwb,
                                                          qb, kvb, qoc, koc, vTc);
    attn<<<dim3(12 * nb, 8), dim3(512), 0, stream>>>(qoc, koc, vTc, aoc);
    gemm_proj<<<dim3(8 * nb, 12), dim3(256), 0, stream>>>(aoc, pwb, pb, (float*)d_out, b0);
  }
}

// Round 16
// 255.272 us; speedup vs baseline: 1.2495x; 1.0249x over previous
//
#include <hip/hip_runtime.h>
#include <stdint.h>

typedef __attribute__((ext_vector_type(4))) float f4;
typedef __attribute__((ext_vector_type(8))) short bf16x8;
typedef __attribute__((ext_vector_type(4))) unsigned short u16x4;
typedef unsigned short u16;

#define B_ 8
#define N_ 1024
#define C_ 768
#define NH 12
#define HD 64

__device__ __forceinline__ float bf2f(u16 v) {
  union { unsigned u; float f; } x; x.u = ((unsigned)v) << 16; return x.f;
}
__device__ __forceinline__ u16 f2bf(float f) {
  union { float f; unsigned u; } x; x.f = f;
  unsigned r = x.u + 0x7FFFu + ((x.u >> 16) & 1u);
  return (u16)(r >> 16);
}
// async global->LDS, 16B per lane
__device__ __forceinline__ void g2l16(const u16* g, const u16* l) {
  __builtin_amdgcn_global_load_lds(
      (const __attribute__((address_space(1))) void*)(uintptr_t)g,
      (__attribute__((address_space(3))) void*)(uint32_t)(uintptr_t)l,
      16, 0, 0);
}

// counted vmem waits (T4): never drain to 0 in the main loop
#define SW12() asm volatile("s_waitcnt vmcnt(12)" ::: "memory")
#define SW6()  asm volatile("s_waitcnt vmcnt(6)" ::: "memory")
#define SW4()  asm volatile("s_waitcnt vmcnt(4)" ::: "memory")
#define SW3()  asm volatile("s_waitcnt vmcnt(3)" ::: "memory")
#define SW2()  asm volatile("s_waitcnt vmcnt(2)" ::: "memory")
#define SW0()  asm volatile("s_waitcnt vmcnt(0)" ::: "memory")
// raw barrier + compile/IR fence (rule #18)
#define BARF()                              \
  do {                                      \
    __builtin_amdgcn_s_barrier();           \
    asm volatile("" ::: "memory");          \
    __builtin_amdgcn_sched_barrier(0);      \
  } while (0)

// ---------------- prep: {LN(y)->y2c} + {cvt x->xbc} + {cvt weights} ------
// blocks [0,32nb): ln path; [32nb,128nb): x cvt; [128nb,128nb+576): weight
// cvt (only when b0==0; segments: 144 qw / 288 kvw / 144 pw blocks).
__global__ __launch_bounds__(512) void prep(const float* __restrict__ y,
                                            const float* __restrict__ lg,
                                            const float* __restrict__ lb,
                                            u16* __restrict__ y2c,
                                            const float* __restrict__ x,
                                            u16* __restrict__ xbc,
                                            const float* __restrict__ qw,
                                            u16* __restrict__ qwb,
                                            const float* __restrict__ kvw,
                                            u16* __restrict__ kvwb,
                                            const float* __restrict__ pw,
                                            u16* __restrict__ pwb,
                                            int b0, int nb, int n4) {
  int t = threadIdx.x;
  int nln = 32 * nb;
  int ncvt0 = 128 * nb;
  if ((int)blockIdx.x >= ncvt0) {
    // ---- weight cvt path (b0==0 launches only) ----
    int wb = blockIdx.x - ncvt0;
    const float* s; u16* d; int nn4, sb, nbk;
    if (wb < 144)      { s = qw;  d = qwb;  nn4 = 147456; sb = 0;   nbk = 144; }
    else if (wb < 432) { s = kvw; d = kvwb; nn4 = 294912; sb = 144; nbk = 288; }
    else               { s = pw;  d = pwb;  nn4 = 147456; sb = 432; nbk = 144; }
    int i = (wb - sb) * 512 + t;
    int stride = nbk * 512;
    for (; i < nn4; i += stride) {
      float4 v = ((const float4*)s)[i];
      u16x4 o;
      o.x = f2bf(v.x); o.y = f2bf(v.y); o.z = f2bf(v.z); o.w = f2bf(v.w);
      ((u16x4*)d)[i] = o;
    }
    return;
  }
  if ((int)blockIdx.x >= nln) {
    // ---- x cvt path ----
    int cb = blockIdx.x - nln;
    int ncvt = ncvt0 - nln;
    int i = cb * 512 + t;
    int stride = ncvt * 512;
    for (; i < n4; i += stride) {
      float4 v = ((const float4*)x)[i];
      u16x4 o;
      o.x = f2bf(v.x); o.y = f2bf(v.y); o.z = f2bf(v.z); o.w = f2bf(v.w);
      ((u16x4*)xbc)[i] = o;
    }
    return;
  }
  // ---- ln path ----
  __shared__ u16 ybuf[768 * 33];          // [c][n 0..31], pitch 33 u16
  __shared__ float ps[16][32], pq[16][32];
  __shared__ float smu[32], srs[32];
  int nl = t & 31, ch = t >> 5;           // 16 c-groups of 48
  int idx0 = b0 * N_ + blockIdx.x * 32;   // flat n-index
  int b = idx0 >> 10, nb_ = idx0 & 1023;
  const float* p = y + (size_t)b * C_ * N_ + nb_ + nl;
  float s = 0.f, q = 0.f;
  int c0 = ch * 48;
  for (int c = c0; c < c0 + 48; ++c) {
    float v = p[(size_t)c * N_];
    s += v; q += v * v;
    ybuf[c * 33 + nl] = f2bf(v);
  }
  ps[ch][nl] = s; pq[ch][nl] = q;
  __syncthreads();
  if (t < 32) {
    float ts = 0.f, tq = 0.f;
    for (int g = 0; g < 16; ++g) { ts += ps[g][t]; tq += pq[g][t]; }
    float m = ts * (1.f / C_);
    float var = tq * (1.f / C_) - m * m;
    smu[t] = m;
    srs[t] = rsqrtf(fmaxf(var, 0.f) + 1e-5f);
  }
  __syncthreads();
  int rn = t >> 4, cg = t & 15;
  float m = smu[rn], rr = srs[rn];
  int bl = b - b0;
  int n = nb_ + rn;
  u16* dst = y2c + ((size_t)bl * N_ + n) * C_ + cg * 48;
  for (int cc = 0; cc < 48; cc += 8) {
    int c = cg * 48 + cc;
    bf16x8 o;
    for (int j = 0; j < 8; ++j) {
      float v = bf2f(ybuf[(c + j) * 33 + rn]);
      o[j] = (short)f2bf((v - m) * rr * lg[c + j] + lb[c + j]);
    }
    *(bf16x8*)(dst + cc) = o;
  }
}

// ---------------- K2: merged dual-A gated GEMM (R5/R11-exact: 90us) ------
// Depth-3 pipeline, counted vmcnt(12), XOR-swizzled LDS, 128x128 tiles.
__global__ __launch_bounds__(256, 2) void gemm_gate(
    const u16* __restrict__ xbc, const u16* __restrict__ y2c,
    const u16* __restrict__ qwb, const u16* __restrict__ kvwb,
    const float* __restrict__ qb_, const float* __restrict__ kvb_,
    u16* __restrict__ o_q, u16* __restrict__ o_k, u16* __restrict__ o_vT) {
  __shared__ u16 smem[36864];  // 3 bufs x 12288 u16 (72 KiB); epilogue reuses front
  int t = threadIdx.x, l = t & 63;
  int quad = l >> 4, l15 = l & 15;
  int w = t >> 6, wm = w & 1, wn = w >> 1;
  int m0l = blockIdx.x * 128;
  int n0l = blockIdx.y * 128;

  const u16* wp; const float* bp; int sel, h0;
  if (n0l < C_) {
    wp = qwb + (size_t)n0l * C_; bp = qb_ + n0l; sel = 0; h0 = n0l >> 6;
  } else {
    int nk = n0l - C_;
    wp = kvwb + (size_t)nk * C_; bp = kvb_ + nk;
    sel = (nk < C_) ? 1 : 2;
    h0 = ((sel == 2) ? nk - C_ : nk) >> 6;
  }

  f4 accx[4][4], accy[4][4];
  for (int i = 0; i < 4; ++i)
    for (int j = 0; j < 4; ++j) {
      accx[i][j] = (f4){0.f, 0.f, 0.f, 0.f};
      accy[i][j] = (f4){0.f, 0.f, 0.f, 0.f};
    }

  int row = t >> 2;
  int colS = (((t & 3) ^ (row & 3)) * 8);   // pre-swizzled source chunk
  const u16* gx = xbc + (size_t)(m0l + row) * C_ + colS;
  const u16* gy = y2c + (size_t)(m0l + row) * C_ + colS;
  const u16* gw = wp + (size_t)row * C_ + colS;
  int rsl = (quad ^ (l15 & 3)) * 8;         // swizzled read slot (u16)

#define STAGE_G(OFF, kk)                                   \
  do {                                                     \
    u16* p_ = smem + (OFF);                                \
    g2l16(gx + (kk),           p_ + t * 8);                \
    g2l16(gx + (kk) + 64 * C_, p_ + 2048 + t * 8);         \
    g2l16(gy + (kk),           p_ + 4096 + t * 8);         \
    g2l16(gy + (kk) + 64 * C_, p_ + 6144 + t * 8);         \
    g2l16(gw + (kk),           p_ + 8192 + t * 8);         \
    g2l16(gw + (kk) + 64 * C_, p_ + 10240 + t * 8);        \
  } while (0)

#define COMPUTE_G(OFF)                                                        \
  do {                                                                        \
    const u16* base = smem + (OFF);                                           \
    bf16x8 afx[4], afy[4], bfr[4];                                            \
    for (int i = 0; i < 4; ++i) {                                             \
      int ra = (wm * 64 + i * 16 + l15) * 32 + rsl;                           \
      afx[i] = *(const bf16x8*)&base[ra];                                     \
      afy[i] = *(const bf16x8*)&base[4096 + ra];                              \
      int rb = (wn * 64 + i * 16 + l15) * 32 + rsl;                           \
      bfr[i] = *(const bf16x8*)&base[8192 + rb];                              \
    }                                                                         \
    for (int i = 0; i < 4; ++i)                                               \
      for (int j = 0; j < 4; ++j) {                                           \
        accx[i][j] = __builtin_amdgcn_mfma_f32_16x16x32_bf16(afx[i], bfr[j], accx[i][j], 0, 0, 0); \
        accy[i][j] = __builtin_amdgcn_mfma_f32_16x16x32_bf16(afy[i], bfr[j], accy[i][j], 0, 0, 0); \
      }                                                                       \
  } while (0)

#define STEP_G(i, OFF)                                        \
  do {                                                        \
    COMPUTE_G(OFF);                                           \
    BARF();                                                   \
    if ((i) < 21)      { STAGE_G(OFF, ((i) + 3) * 32); SW12(); } \
    else if ((i) == 21) SW6();                                \
    else if ((i) == 22) SW0();                                \
    BARF();                                                   \
  } while (0)

  STAGE_G(0, 0);
  STAGE_G(12288, 32);
  STAGE_G(24576, 64);
  SW12();   // tile0 done (tiles 1,2 in flight)
  BARF();
#pragma unroll
  for (int n = 0; n < 24; n += 3) {
    STEP_G(n, 0);
    STEP_G(n + 1, 12288);
    STEP_G(n + 2, 24576);
  }
#undef STEP_G
#undef STAGE_G
#undef COMPUTE_G

  // epilogue: gate -> LDS tile -> cached 16-B stores
  const int PITCH = 136;
  for (int j = 0; j < 4; ++j) {
    int cloc = wn * 64 + j * 16 + l15;
    float bias = bp[cloc];
    for (int i = 0; i < 4; ++i) {
      int rb0 = wm * 64 + i * 16 + quad * 4;
      for (int r = 0; r < 4; ++r) {
        int rloc = rb0 + r;
        float vx = accx[i][j][r] + bias;
        float vy = accy[i][j][r] + bias;
        float gg = 1.f / (1.f + __expf(-vy));
        float val = (sel == 0) ? vx * (1.f + gg) : gg * (vx + 1.f);
        u16 bv = f2bf(val);
        if (sel == 2) smem[cloc * PITCH + rloc] = bv;   // v staged transposed
        else          smem[rloc * PITCH + cloc] = bv;
      }
    }
  }
  __syncthreads();
  {
    int rr = t >> 1, hh = t & 1;
    const u16* src = smem + rr * PITCH + hh * 64;
    u16* dst;
    if (sel == 2) {
      int h = h0 + (rr >> 6), d = rr & 63;
      int bl = m0l >> 10, nbase = m0l & 1023;
      dst = o_vT + (size_t)((bl * NH + h) * HD + d) * N_ + nbase + hh * 64;
    } else {
      int gml = m0l + rr;
      int bl = gml >> 10, n = gml & 1023;
      int h = h0 + hh;
      dst = (sel == 0 ? o_q : o_k) + (size_t)((bl * NH + h) * N_ + n) * HD;
    }
    for (int c = 0; c < 8; ++c) {
      bf16x8 v = *(const bf16x8*)(src + c * 8);
      *(bf16x8*)(dst + c * 8) = v;
    }
  }
}

// ---------------- K3: fused attention, depth-3 KV pipeline ---------------
// XCD-locality grid (heads, qblocks). Q fragments loaded once per wave
// directly from global (no cross-block Q reuse -> no R12 hazard). K/V use
// gate's proven depth-3 STEP: stage kt+3 after the read-done barrier,
// counted SW4 waits only kt+1's 2 loads (kt+2, kt+3 stay in flight).
// LDS: 3x(K 8KB + V 8KB) + Ps 18KB = 66KB -> 2 blocks/CU.
__global__ __launch_bounds__(512) void attn(const u16* __restrict__ qoc,
                                            const u16* __restrict__ koc,
                                            const u16* __restrict__ vTc,
                                            u16* __restrict__ aoc) {
  __shared__ u16 Ks[12288], Vs[12288];    // 3 bufs x 4096 u16 each
  __shared__ u16 Ps[128 * 72];
  int t = threadIdx.x, l = t & 63, w = t >> 6;   // w: 0..7
  int quad = l >> 4, l15 = l & 15;
  int bhl = blockIdx.x;                  // head index (B*NH)
  int bl = bhl / NH, h = bhl % NH;
  int q0 = blockIdx.y * 128;             // q-block
  int sr = t >> 3;                       // staging row 0..63
  int swo = ((t & 7) ^ (sr & 7)) * 8;    // swizzled source chunk offset (u16)
  const u16* qbp = qoc + ((size_t)bhl * N_ + q0) * HD;
  const u16* kb = koc + (size_t)bhl * N_ * HD;
  const u16* vb = vTc + (size_t)bhl * HD * N_;

#define STAGE_KV(OFF, key0)                                                \
  do {                                                                     \
    g2l16(kb + (size_t)((key0) + sr) * HD + swo, Ks + (OFF) + t * 8);      \
    g2l16(vb + (size_t)sr * N_ + (key0) + swo,   Vs + (OFF) + t * 8);      \
  } while (0)

  STAGE_KV(0, 0);
  STAGE_KV(4096, 64);
  STAGE_KV(8192, 128);
  // Q fragments direct from global (once per wave; L2-hot from gemm_gate)
  const u16* qrow = qbp + (size_t)(w * 16 + l15) * HD;
  bf16x8 aq0 = *(const bf16x8*)(qrow + quad * 8);
  bf16x8 aq1 = *(const bf16x8*)(qrow + 32 + quad * 8);
  SW4();   // kt0's 2 loads done (kt1, kt2 in flight)
  BARF();

  int sA = (quad ^ (l15 & 7)) * 8;  // swizzled slot, contraction chunks 0-3
  int sB = sA ^ 32;                 // chunks 4-7
  f4 o[4];
  for (int i = 0; i < 4; ++i) o[i] = (f4){0.f, 0.f, 0.f, 0.f};
  f4 ls = (f4){0.f, 0.f, 0.f, 0.f};
  bf16x8 ones;
  for (int i = 0; i < 8; ++i) ones[i] = (short)0x3F80;  // bf16 1.0

#define TILE_STEP(KOFF)                                                       \
  do {                                                                        \
    f4 s_[4];                                                                 \
    __builtin_amdgcn_s_setprio(1);                                            \
    for (int ni = 0; ni < 4; ++ni) {                                          \
      bf16x8 b0v = *(const bf16x8*)&Ks[(KOFF) + (ni * 16 + l15) * 64 + sA];   \
      bf16x8 b1v = *(const bf16x8*)&Ks[(KOFF) + (ni * 16 + l15) * 64 + sB];   \
      f4 z = (f4){0.f, 0.f, 0.f, 0.f};                                        \
      z = __builtin_amdgcn_mfma_f32_16x16x32_bf16(aq0, b0v, z, 0, 0, 0);      \
      z = __builtin_amdgcn_mfma_f32_16x16x32_bf16(aq1, b1v, z, 0, 0, 0);      \
      s_[ni] = z;                                                             \
    }                                                                         \
    __builtin_amdgcn_s_setprio(0);                                            \
    for (int ni = 0; ni < 4; ++ni)                                            \
      for (int r = 0; r < 4; ++r)                                             \
        Ps[(w * 16 + quad * 4 + r) * 72 + ni * 16 + l15] =                    \
            f2bf(__expf(s_[ni][r] * 0.125f));                                 \
    bf16x8 ap0 = *(const bf16x8*)&Ps[(w * 16 + l15) * 72 + quad * 8];         \
    bf16x8 ap1 = *(const bf16x8*)&Ps[(w * 16 + l15) * 72 + 32 + quad * 8];    \
    __builtin_amdgcn_s_setprio(1);                                            \
    for (int ni = 0; ni < 4; ++ni) {                                          \
      bf16x8 b0v = *(const bf16x8*)&Vs[(KOFF) + (ni * 16 + l15) * 64 + sA];   \
      bf16x8 b1v = *(const bf16x8*)&Vs[(KOFF) + (ni * 16 + l15) * 64 + sB];   \
      o[ni] = __builtin_amdgcn_mfma_f32_16x16x32_bf16(ap0, b0v, o[ni], 0, 0, 0); \
      o[ni] = __builtin_amdgcn_mfma_f32_16x16x32_bf16(ap1, b1v, o[ni], 0, 0, 0); \
    }                                                                         \
    ls = __builtin_amdgcn_mfma_f32_16x16x32_bf16(ap0, ones, ls, 0, 0, 0);     \
    ls = __builtin_amdgcn_mfma_f32_16x16x32_bf16(ap1, ones, ls, 0, 0, 0);     \
    __builtin_amdgcn_s_setprio(0);                                            \
  } while (0)

// step k: compute buf, barrier (all done reading), restage buf with kt=k+3,
// counted wait for kt=k+1, barrier (kt=k+1 visible everywhere).
#define STEP_A(k, OFF)                                        \
  do {                                                        \
    TILE_STEP(OFF);                                           \
    BARF();                                                   \
    if ((k) + 3 < 16)   { STAGE_KV(OFF, ((k) + 3) * 64); SW4(); } \
    else if ((k) == 13) SW2();                                \
    else if ((k) == 14) SW0();                                \
    BARF();                                                   \
  } while (0)

  for (int kt = 0; kt < 15; kt += 3) {
    STEP_A(kt, 0);
    STEP_A(kt + 1, 4096);
    STEP_A(kt + 2, 8192);
  }
  STEP_A(15, 0);
#undef STEP_A
#undef TILE_STEP
#undef STAGE_KV

  for (int ni = 0; ni < 4; ++ni)
    for (int r = 0; r < 4; ++r)
      Ps[(w * 16 + quad * 4 + r) * 72 + ni * 16 + l15] =
          f2bf(o[ni][r] / ls[r]);
  __syncthreads();
  {
    int rr = t >> 2, cc = t & 3;               // 128 rows x 4 chunks of 16
    int n = q0 + rr;
    const u16* src = Ps + rr * 72 + cc * 16;
    u16* dst = aoc + ((size_t)bl * N_ + n) * C_ + h * HD + cc * 16;
    *(bf16x8*)dst = *(const bf16x8*)src;
    *(bf16x8*)(dst + 8) = *(const bf16x8*)(src + 8);
  }
}

// ---------------- K4: output projection GEMM, BK=64 depth-2 (R11) --------
__global__ __launch_bounds__(256, 2) void gemm_proj(const u16* __restrict__ aoc,
                                                    const u16* __restrict__ pwb,
                                                    const float* __restrict__ bias,
                                                    float* __restrict__ out,
                                                    int b0) {
  __shared__ u16 smem[24576];  // 2 bufs x 12288 (A 128x64 + B 64x64)
  int t = threadIdx.x, l = t & 63;
  int quad = l >> 4, l15 = l & 15;
  int w = t >> 6, wm = w & 1, wn = w >> 1;
  int m0l = blockIdx.x * 128, n0 = blockIdx.y * 64;
  f4 acc[4][2];
  for (int i = 0; i < 4; ++i)
    for (int j = 0; j < 2; ++j) acc[i][j] = (f4){0.f, 0.f, 0.f, 0.f};
  int row = t >> 2, colb = (t & 3) * 8;
  const u16* ga = aoc + (size_t)(m0l + row) * C_ + colb;
  const u16* gw = pwb + (size_t)(n0 + row) * C_ + colb;

#define STAGE_P(OFF, kk)                                        \
  do {                                                          \
    u16* p_ = smem + (OFF);                                     \
    g2l16(ga + (kk),                p_ + t * 8);                \
    g2l16(ga + (kk) + 64 * C_,      p_ + 2048 + t * 8);         \
    g2l16(ga + (kk) + 32,           p_ + 4096 + t * 8);         \
    g2l16(ga + (kk) + 32 + 64 * C_, p_ + 6144 + t * 8);         \
    g2l16(gw + (kk),                p_ + 8192 + t * 8);         \
    g2l16(gw + (kk) + 32,           p_ + 10240 + t * 8);        \
  } while (0)

#define COMPUTE_P(OFF)                                                        \
  do {                                                                        \
    const u16* base = smem + (OFF);                                           \
    _Pragma("unroll")                                                         \
    for (int kh = 0; kh < 2; ++kh) {                                          \
      bf16x8 af[4], bfr[2];                                                   \
      for (int i = 0; i < 4; ++i)                                             \
        af[i] = *(const bf16x8*)&base[kh * 4096 + (wm * 64 + i * 16 + l15) * 32 + quad * 8]; \
      for (int j = 0; j < 2; ++j)                                             \
        bfr[j] = *(const bf16x8*)&base[8192 + kh * 2048 + (wn * 32 + j * 16 + l15) * 32 + quad * 8]; \
      for (int i = 0; i < 4; ++i)                                             \
        for (int j = 0; j < 2; ++j)                                           \
          acc[i][j] = __builtin_amdgcn_mfma_f32_16x16x32_bf16(af[i], bfr[j], acc[i][j], 0, 0, 0); \
    }                                                                         \
  } while (0)

  STAGE_P(0, 0);
  STAGE_P(12288, 64);
  SW6();
  BARF();
  for (int n = 0; n < 12; n += 2) {
    COMPUTE_P(0);
    BARF();
    if (n + 2 < 12) { STAGE_P(0, (n + 2) * 64); SW6(); } else { SW0(); }
    BARF();
    COMPUTE_P(12288);
    BARF();
    if (n + 3 < 12) { STAGE_P(12288, (n + 3) * 64); SW6(); } else { SW0(); }
    BARF();
  }
#undef STAGE_P
#undef COMPUTE_P

  for (int j = 0; j < 2; ++j) {
    int gcol = n0 + wn * 32 + j * 16 + l15;
    float bv = bias[gcol];
    for (int i = 0; i < 4; ++i) {
      int rbase = m0l + wm * 64 + i * 16 + quad * 4;
      for (int r = 0; r < 4; ++r)
        __builtin_nontemporal_store(acc[i][j][r] + bv,
                                    &out[(size_t)(b0 * N_ + rbase + r) * C_ + gcol]);
    }
  }
}

extern "C" void kernel_launch(void* const* d_in, const int* in_sizes, int n_in,
                              void* d_out, int out_size, void* d_ws, size_t ws_size,
                              hipStream_t stream) {
  const float* x   = (const float*)d_in[0];
  const float* y   = (const float*)d_in[1];
  const float* qw  = (const float*)d_in[2];
  const float* qb  = (const float*)d_in[3];
  const float* kvw = (const float*)d_in[4];
  const float* kvb = (const float*)d_in[5];
  const float* pw  = (const float*)d_in[6];
  const float* pb  = (const float*)d_in[7];
  const float* lg  = (const float*)d_in[8];
  const float* lb  = (const float*)d_in[9];

  char* ws = (char*)d_ws;
  u16* qwb  = (u16*)(ws + 65536);
  u16* kvwb = (u16*)(ws + 1245184);
  u16* pwb  = (u16*)(ws + 3604480);
  const size_t BASE2 = 4784128;
  const size_t PER_B = 1572864;

  int nb = 1;
  for (int c = 8; c >= 1; c >>= 1) {
    if (BASE2 + 5 * (size_t)c * PER_B <= ws_size) { nb = c; break; }
  }
  u16* xbc = (u16*)(ws + BASE2);
  u16* y2c = (u16*)(ws + BASE2 + (size_t)nb * PER_B);
  u16* qoc = (u16*)(ws + BASE2 + 2 * (size_t)nb * PER_B);
  u16* koc = (u16*)(ws + BASE2 + 3 * (size_t)nb * PER_B);
  u16* vTc = (u16*)(ws + BASE2 + 4 * (size_t)nb * PER_B);
  u16* aoc = xbc;

  for (int b0 = 0; b0 < B_; b0 += nb) {
    int nblk = 128 * nb + (b0 == 0 ? 576 : 0);
    prep<<<dim3(nblk), dim3(512), 0, stream>>>(
        y, lg, lb, y2c, x + (size_t)b0 * N_ * C_, xbc,
        qw, qwb, kvw, kvwb, pw, pwb, b0, nb, nb * 196608);
    gemm_gate<<<dim3(8 * nb, 18), dim3(256), 0, stream>>>(xbc, y2c, qwb, kvwb,
                                                          qb, kvb, qoc, koc, vTc);
    attn<<<dim3(12 * nb, 8), dim3(512), 0, stream>>>(qoc, koc, vTc, aoc);
    gemm_proj<<<dim3(8 * nb, 12), dim3(256), 0, stream>>>(aoc, pwb, pb, (float*)d_out, b0);
  }
}